// Round 4
// baseline (829.044 us; speedup 1.0000x reference)
//
#include <hip/hip_runtime.h>
#include <hip/hip_bf16.h>
#include <math.h>

using bf16 = __hip_bfloat16;
typedef __attribute__((ext_vector_type(8))) __bf16 bf16x8;
typedef __attribute__((ext_vector_type(4))) float f32x4;

__device__ __forceinline__ float b2f(bf16 x){ return __bfloat162float(x); }
__device__ __forceinline__ bf16  f2b(float x){ return __float2bfloat16(x); }
__device__ __forceinline__ float ldf(const float* p, size_t i){ return p[i]; }
__device__ __forceinline__ float ldf(const bf16*  p, size_t i){ return b2f(p[i]); }
__device__ __forceinline__ void stf(float* p, size_t i, float v){ p[i] = v; }
__device__ __forceinline__ void stf(bf16*  p, size_t i, float v){ p[i] = f2b(v); }

// fast gelu: tanh form, |err| ~1e-3
__device__ __forceinline__ float gelu_f(float v){
  float u = v*(0.7978845608f + 0.0356774081f*v*v);
  float e = __expf(2.f*u);
  float t = 1.f - 2.f/(e+1.f);          // tanh(u); saturates correctly at +-inf
  return 0.5f*v*(1.f+t);
}

// async 16B global->LDS (LDS base must be wave-uniform; HW adds lane*16)
typedef const __attribute__((address_space(1))) unsigned int* gas_u32p;
typedef __attribute__((address_space(3))) unsigned int* las_u32p;
__device__ __forceinline__ void gl_lds16(const bf16* g, bf16* l){
  __builtin_amdgcn_global_load_lds((gas_u32p)(const void*)g, (las_u32p)(void*)l, 16, 0, 0);
}

#define MFMA16 __builtin_amdgcn_mfma_f32_16x16x32_bf16

// counted LDS wait + scheduler fence (rule #18: fence required after lgkmcnt)
#define LGKM(N) do { \
  asm volatile("s_waitcnt lgkmcnt(" #N ")" ::: "memory"); \
  __builtin_amdgcn_sched_barrier(0); \
} while(0)

#define NHEAD 12
#define HDIM  64
#define HID   768
#define SEQ   512
#define BATCH 32
#define ROWS  (BATCH*SEQ)   // 16384
#define QKVW  2304          // packed qkv row width
#define QCH   128           // q-chunk rows for attention
#define NCHUNK (SEQ/QCH)    // 4
#define FT    128           // flash key tile
#define LOG2E 1.44269504f

// ---------------------------------------------------------------------------
// 256x256 8-phase MFMA GEMM (T2+T3+T4+T5): C[M,N] = A[M,K]*Bt[N,K]^T +bias.
// (unchanged from round 3: counted lgkmcnt chunked MFMA, 1 barrier/phase)
// ---------------------------------------------------------------------------
template<int EPI, typename TR>
__global__ __launch_bounds__(512,2)
void gemm8p(const bf16* __restrict__ A, int lda,
            const bf16* __restrict__ Bt, int ldb,
            bf16* __restrict__ C, int ldc, int K,
            const float* __restrict__ bias,
            const TR* __restrict__ res, int ldres)
{
  __shared__ __align__(16) bf16 tileLds[4][256*64];   // [buf*2 + (0=A,1=B)]

  const int tid  = threadIdx.x;
  const int wave = tid>>6, lane = tid&63;
  const int r = lane&15, qd = lane>>4;
  const int wr = wave>>2, wc = wave&3;        // 2M x 4N waves
  const int m0 = blockIdx.y*256, n0 = blockIdx.x*256;
  const int NTK = K>>6;
  const int wbase = wave*512;                 // per-wave LDS element base

  const int sr = tid>>3, sp = tid&7;
  const bf16* pA = A  + (size_t)(m0+sr)*lda + ((sp^(sr&7))<<3);
  const bf16* pB = Bt + (size_t)(n0+sr)*ldb + ((sp^(sr&7))<<3);

  auto stage = [&](int H){
    const int u = H>>2, idx = H&3, bufi = u&1;
    const size_t kof = (size_t)u*64;
    if (idx==0){            // A half0
      gl_lds16(pA + kof,                    tileLds[bufi*2] + wbase);
      gl_lds16(pA + kof + (size_t)64*lda,   tileLds[bufi*2] + wbase + 4096);
    } else if (idx==3){     // A half1
      gl_lds16(pA + kof + (size_t)128*lda,  tileLds[bufi*2] + 8192 + wbase);
      gl_lds16(pA + kof + (size_t)192*lda,  tileLds[bufi*2] + 8192 + wbase + 4096);
    } else {                // B half (idx1->h0, idx2->h1)
      const int h = idx-1;
      gl_lds16(pB + kof + (size_t)(h*128)*ldb,
               tileLds[bufi*2+1] + h*8192 + wbase);
      gl_lds16(pB + kof + (size_t)(h*128+64)*ldb,
               tileLds[bufi*2+1] + h*8192 + wbase + 4096);
    }
  };

  auto rdA = [&](const bf16* base, int mi, int ks)->bf16x8{
    const int row = mi*32 + wr*16 + r;
    return *(const bf16x8*)(base + row*64 + ((((ks<<2)|qd) ^ (r&7))<<3));
  };
  auto rdB = [&](const bf16* base, int nj, int ks)->bf16x8{
    const int row = nj*64 + wc*16 + r;
    return *(const bf16x8*)(base + row*64 + ((((ks<<2)|qd) ^ (r&7))<<3));
  };

  #pragma unroll
  for (int H=0; H<7; ++H) stage(H);
  asm volatile("s_waitcnt vmcnt(6)" ::: "memory");
  __builtin_amdgcn_s_barrier();

  f32x4 acc[8][4] = {};

  for (int t=0; t<NTK; ++t){
    const bf16* a = tileLds[(t&1)*2];
    const bf16* b = tileLds[(t&1)*2+1];
    const int Hb = 4*t + 6;
    const int Hmax = 4*NTK;
    bf16x8 af[4][2], bn0[2][2], bn1[2][2];

    // ---- phase 1: quadrant (m0,n0); 12 reads; stage (t+1) A1
    af[0][0]=rdA(a,0,0); af[0][1]=rdA(a,0,1);
    af[1][0]=rdA(a,1,0); af[1][1]=rdA(a,1,1);
    bn0[0][0]=rdB(b,0,0); bn0[0][1]=rdB(b,0,1);
    bn0[1][0]=rdB(b,1,0); bn0[1][1]=rdB(b,1,1);
    __builtin_amdgcn_sched_barrier(0);
    af[2][0]=rdA(a,2,0); af[2][1]=rdA(a,2,1);
    af[3][0]=rdA(a,3,0); af[3][1]=rdA(a,3,1);
    if (Hb+1 < Hmax) stage(Hb+1);
    LGKM(4);                               // first 8 reads landed
    __builtin_amdgcn_s_setprio(1);
    #pragma unroll
    for (int mi=0;mi<2;mi++)
      #pragma unroll
      for (int nj=0;nj<2;nj++){
        acc[mi][nj] = MFMA16(af[mi][0], bn0[nj][0], acc[mi][nj],0,0,0);
        acc[mi][nj] = MFMA16(af[mi][1], bn0[nj][1], acc[mi][nj],0,0,0);
      }
    LGKM(0);                               // af[2..3] landed
    #pragma unroll
    for (int mi=2;mi<4;mi++)
      #pragma unroll
      for (int nj=0;nj<2;nj++){
        acc[mi][nj] = MFMA16(af[mi][0], bn0[nj][0], acc[mi][nj],0,0,0);
        acc[mi][nj] = MFMA16(af[mi][1], bn0[nj][1], acc[mi][nj],0,0,0);
      }
    __builtin_amdgcn_s_setprio(0);
    __builtin_amdgcn_s_barrier();

    // ---- phase 2: quadrant (m0,n1); 4 reads; stage (t+2) A0
    bn1[0][0]=rdB(b,2,0); bn1[0][1]=rdB(b,2,1);
    __builtin_amdgcn_sched_barrier(0);
    bn1[1][0]=rdB(b,3,0); bn1[1][1]=rdB(b,3,1);
    if (Hb+2 < Hmax) stage(Hb+2);
    LGKM(2);
    __builtin_amdgcn_s_setprio(1);
    #pragma unroll
    for (int mi=0;mi<4;mi++){
      acc[mi][2] = MFMA16(af[mi][0], bn1[0][0], acc[mi][2],0,0,0);
      acc[mi][2] = MFMA16(af[mi][1], bn1[0][1], acc[mi][2],0,0,0);
    }
    LGKM(0);
    #pragma unroll
    for (int mi=0;mi<4;mi++){
      acc[mi][3] = MFMA16(af[mi][0], bn1[1][0], acc[mi][3],0,0,0);
      acc[mi][3] = MFMA16(af[mi][1], bn1[1][1], acc[mi][3],0,0,0);
    }
    __builtin_amdgcn_s_setprio(0);
    __builtin_amdgcn_s_barrier();

    // ---- phase 3: quadrant (m1,n1); 8 reads (af := m1); stage (t+2) B0
    af[0][0]=rdA(a,4,0); af[0][1]=rdA(a,4,1);
    af[1][0]=rdA(a,5,0); af[1][1]=rdA(a,5,1);
    __builtin_amdgcn_sched_barrier(0);
    af[2][0]=rdA(a,6,0); af[2][1]=rdA(a,6,1);
    af[3][0]=rdA(a,7,0); af[3][1]=rdA(a,7,1);
    if (Hb+3 < Hmax) stage(Hb+3);
    LGKM(4);
    __builtin_amdgcn_s_setprio(1);
    #pragma unroll
    for (int mi=0;mi<2;mi++)
      #pragma unroll
      for (int nj=0;nj<2;nj++){
        acc[4+mi][2+nj] = MFMA16(af[mi][0], bn1[nj][0], acc[4+mi][2+nj],0,0,0);
        acc[4+mi][2+nj] = MFMA16(af[mi][1], bn1[nj][1], acc[4+mi][2+nj],0,0,0);
      }
    LGKM(0);
    #pragma unroll
    for (int mi=2;mi<4;mi++)
      #pragma unroll
      for (int nj=0;nj<2;nj++){
        acc[4+mi][2+nj] = MFMA16(af[mi][0], bn1[nj][0], acc[4+mi][2+nj],0,0,0);
        acc[4+mi][2+nj] = MFMA16(af[mi][1], bn1[nj][1], acc[4+mi][2+nj],0,0,0);
      }
    __builtin_amdgcn_s_setprio(0);
    __builtin_amdgcn_s_barrier();

    // ---- phase 4: quadrant (m1,n0); 0 reads (af=m1, bn0 live); stage (t+2) B1
    if (Hb+4 < Hmax) stage(Hb+4);
    __builtin_amdgcn_s_setprio(1);
    #pragma unroll
    for (int mi=0;mi<4;mi++)
      #pragma unroll
      for (int nj=0;nj<2;nj++){
        acc[4+mi][nj] = MFMA16(af[mi][0], bn0[nj][0], acc[4+mi][nj],0,0,0);
        acc[4+mi][nj] = MFMA16(af[mi][1], bn0[nj][1], acc[4+mi][nj],0,0,0);
      }
    __builtin_amdgcn_s_setprio(0);
    if (t < NTK-2) { asm volatile("s_waitcnt vmcnt(6)" ::: "memory"); }
    else           { asm volatile("s_waitcnt vmcnt(0)" ::: "memory"); }
    __builtin_amdgcn_s_barrier();
  }

  // epilogue
  float bs[4];
  #pragma unroll
  for (int nj=0;nj<4;nj++)
    bs[nj] = bias ? bias[n0 + nj*64 + wc*16 + r] : 0.f;
  #pragma unroll
  for (int mi=0;mi<8;mi++){
    #pragma unroll
    for (int nj=0;nj<4;nj++){
      #pragma unroll
      for (int i=0;i<4;i++){
        const int mm = m0 + mi*32 + wr*16 + qd*4 + i;
        const int nn = n0 + nj*64 + wc*16 + r;
        float v = acc[mi][nj][i] + bs[nj];
        if (EPI==1) v = gelu_f(v);
        if (EPI==2) v += ldf(res, (size_t)mm*ldres + nn);
        C[(size_t)mm*ldc + nn] = f2b(v);
      }
    }
  }
}

// ---------------------------------------------------------------------------
// Fused flash attention v2: one block = one (b,h) x 128-row q-chunk.
// Round-4 changes vs round-3 (theory: barrier-convoy + LDS-scalar bound,
// MfmaUtil 8.6%):
//  - Q hoisted to registers (fragment-layout global loads); Qs LDS deleted.
//  - Ps is a SEPARATE 16KB buffer (no Ks alias): P write->read is wave-local,
//    ordered by lgkmcnt only => 4 of 6 per-tile barriers removed.
//  - pipelined staging: K(t+1) issued after post-QK^T barrier (flies under
//    softmax+PV); V(t+1) issued after post-PV barrier. 3 barriers/tile.
//    Hazards: K refill after all-waves QK^T reads (barrier A); V refill after
//    all-waves PV reads (barrier B); loads drained by syncthreads vmcnt(0).
//  - mask kept in 8 regs (per-lane global loads; no smask LDS, saves 64
//    scalar LDS reads/lane/tile); softmax in exp2 domain (1 v_exp_f32).
// LDS: Ks 16K + Vts 16K + Ps 16K = 48KB -> 3 blocks/CU.
// ---------------------------------------------------------------------------
__global__ __launch_bounds__(256)
void flash_attn(const bf16* __restrict__ qkv, const bf16* __restrict__ vtb,
                const float* __restrict__ mask, bf16* __restrict__ ctx)
{
  const int qc = blockIdx.x;
  const int z  = blockIdx.y;
  const int b  = z / NHEAD, h = z - b*NHEAD;
  const int q0 = qc*QCH;

  __shared__ __align__(16) bf16 Ks[FT*64];
  __shared__ __align__(16) bf16 Vts[64*FT];
  __shared__ __align__(16) bf16 Ps[QCH*64];

  const int tid = threadIdx.x;
  const int wave = tid>>6, lane = tid&63;
  const int r = lane&15, qd = lane>>4;
  const int wr = wave;                        // wave owns q-rows wr*32..+32

  const bf16* Qg = qkv + ((size_t)(b*SEQ + q0))*QKVW + h*HDIM;
  const bf16* Kg = qkv + ((size_t)b*SEQ)*QKVW + 768 + h*HDIM;
  const bf16* Vg = vtb + (size_t)z*HDIM*SEQ;

  auto stageK = [&](int k0){
    #pragma unroll
    for (int c0=0;c0<1024;c0+=256){          // K tile 128 rows x 8 chunks
      int c = c0+tid, row = c>>3, pos = c&7;
      gl_lds16(Kg + (size_t)(k0+row)*QKVW + ((pos^(row&7))*8),
               Ks + (size_t)(c0 + wave*64)*8);
    }
  };
  auto stageV = [&](int k0){
    #pragma unroll
    for (int c0=0;c0<1024;c0+=256){          // Vt tile 64 rows x 16 chunks
      int c = c0+tid, row = c>>4, pos = c&15;
      gl_lds16(Vg + (size_t)row*SEQ + k0 + ((pos^(row&7))*8),
               Vts + (size_t)(c0 + wave*64)*8);
    }
  };

  // prologue: stage tile 0, Q -> registers (fragment layout, no swizzle)
  stageK(0);
  stageV(0);
  bf16x8 qf[2][2];
  #pragma unroll
  for (int mi=0;mi<2;mi++)
    #pragma unroll
    for (int ks=0;ks<2;ks++)
      qf[mi][ks] = *(const bf16x8*)(Qg + (size_t)(wr*32+mi*16+r)*QKVW + (ks*4+qd)*8);

  f32x4 accO[2][4] = {};             // rows wr*32+mi*16+qd*4+i ; col d=ni*16+r
  float mrun[2][4], lrun[2][4];
  #pragma unroll
  for (int a=0;a<2;a++)
    #pragma unroll
    for (int i2=0;i2<4;i2++){ mrun[a][i2]=-1e30f; lrun[a][i2]=0.f; }

  const float SC2 = 0.125f*LOG2E;

  for (int k0=0; k0<SEQ; k0+=FT){
    __syncthreads();                 // K(t),V(t) landed (vmcnt0 in syncthreads)

    // mask for this tile -> regs (L2/L3-resident; consumed in softmax)
    float mk[8];
    #pragma unroll
    for (int ni=0;ni<8;ni++)
      mk[ni] = mask[(size_t)b*SEQ + k0 + ni*16 + r] * LOG2E;

    // S = Q K^T : this wave M=32, N=128, K=64 (Q in regs, K from LDS)
    f32x4 accS[2][8] = {};
    #pragma unroll
    for (int ks=0; ks<2; ks++){
      bf16x8 bfv[8];
      #pragma unroll
      for (int ni=0;ni<8;ni++){
        int row = ni*16 + r;
        int jr = ks*4 + qd;
        bfv[ni] = *(const bf16x8*)(Ks + row*64 + ((jr^(row&7))*8));
      }
      #pragma unroll
      for (int mi=0;mi<2;mi++)
        #pragma unroll
        for (int ni=0;ni<8;ni++)
          accS[mi][ni] = MFMA16(qf[mi][ks], bfv[ni], accS[mi][ni], 0,0,0);
    }

    __syncthreads();                 // barrier A: all waves done reading Ks
    if (k0+FT < SEQ) stageK(k0+FT);  // K(t+1) flies under softmax+PV

    // online softmax (exp2 domain; row stats via shfl over r lanes)
    #pragma unroll
    for (int mi=0;mi<2;mi++){
      #pragma unroll
      for (int i=0;i<4;i++){
        float mx = -1e30f;
        #pragma unroll
        for (int ni=0;ni<8;ni++){
          float v = accS[mi][ni][i]*SC2 + mk[ni];
          accS[mi][ni][i] = v;
          mx = fmaxf(mx, v);
        }
        #pragma unroll
        for (int off=1; off<16; off<<=1) mx = fmaxf(mx, __shfl_xor(mx, off));
        float mnew = fmaxf(mrun[mi][i], mx);
        float alpha = exp2f(mrun[mi][i] - mnew);
        mrun[mi][i] = mnew;
        float ssum = 0.f;
        #pragma unroll
        for (int ni=0;ni<8;ni++){
          float p = exp2f(accS[mi][ni][i] - mnew);
          accS[mi][ni][i] = p;
          ssum += p;
        }
        #pragma unroll
        for (int off=1; off<16; off<<=1) ssum += __shfl_xor(ssum, off);
        lrun[mi][i] = lrun[mi][i]*alpha + ssum;
        #pragma unroll
        for (int ni=0;ni<4;ni++) accO[mi][ni][i] *= alpha;
      }
    }

    // P -> Ps (own rows; separate buffer => wave-local, lgkm-ordered), 2 halves
    #pragma unroll
    for (int half=0; half<2; half++){
      #pragma unroll
      for (int mi=0;mi<2;mi++){
        #pragma unroll
        for (int i=0;i<4;i++){
          int row = wr*32 + mi*16 + qd*4 + i;
          #pragma unroll
          for (int nj=0;nj<4;nj++){
            int colL = nj*16 + r;
            int chunk = colL>>3;
            Ps[row*64 + ((chunk^(row&7))*8) + (colL&7)] = f2b(accS[mi][half*4+nj][i]);
          }
        }
      }
      // PV: O += P[half] * V[half]  (Ps own rows; Vts stable this tile)
      #pragma unroll
      for (int ks=0; ks<2; ks++){
        bf16x8 af[2], bfv[4];
        #pragma unroll
        for (int mi=0;mi<2;mi++){
          int row = wr*32 + mi*16 + r;
          int jr = ks*4 + qd;
          af[mi] = *(const bf16x8*)(Ps + row*64 + ((jr^(row&7))*8));
        }
        #pragma unroll
        for (int ni=0;ni<4;ni++){
          int row = ni*16 + r;
          int jrv = half*8 + ks*4 + qd;
          bfv[ni] = *(const bf16x8*)(Vts + row*FT + ((jrv^(row&7))*8));
        }
        #pragma unroll
        for (int mi=0;mi<2;mi++)
          #pragma unroll
          for (int ni=0;ni<4;ni++)
            accO[mi][ni] = MFMA16(af[mi], bfv[ni], accO[mi][ni], 0,0,0);
      }
    }

    __syncthreads();                 // barrier B: all waves done reading Vts
    if (k0+FT < SEQ) stageV(k0+FT);  // V(t+1); drained at next loop-top sync
  }

  bf16* Cg = ctx + ((size_t)(b*SEQ + q0))*HID + h*HDIM;
  #pragma unroll
  for (int mi=0;mi<2;mi++)
    #pragma unroll
    for (int i=0;i<4;i++){
      int row = wr*32 + mi*16 + qd*4 + i;
      float invl = 1.0f/lrun[mi][i];
      #pragma unroll
      for (int ni=0;ni<4;ni++)
        Cg[(size_t)row*HID + ni*16 + r] = f2b(accO[mi][ni][i]*invl);
    }
}

// ---------------------------------------------------------------------------
// Weight transpose + fp32->bf16 cast (unchanged)
// ---------------------------------------------------------------------------
__global__ void transpose_cast(const float* __restrict__ in, bf16* __restrict__ out,
                               int R, int C)
{
  __shared__ float tile[32][33];
  int bc = blockIdx.x*32, br = blockIdx.y*32;
  int tx = threadIdx.x, ty = threadIdx.y;
  #pragma unroll
  for (int i=ty;i<32;i+=8)
    tile[i][tx] = in[(size_t)(br+i)*C + bc+tx];
  __syncthreads();
  #pragma unroll
  for (int i=ty;i<32;i+=8)
    out[(size_t)(bc+i)*R + br+tx] = f2b(tile[tx][i]);
}

__global__ void transpose_cast4(const float* __restrict__ w0, const float* __restrict__ w1,
                                const float* __restrict__ w2, const float* __restrict__ w3,
                                bf16* __restrict__ out)
{
  const float* in = blockIdx.z==0?w0 : blockIdx.z==1?w1 : blockIdx.z==2?w2 : w3;
  bf16* o = out + (size_t)blockIdx.z*768*768;
  __shared__ float tile[32][33];
  int bc = blockIdx.x*32, br = blockIdx.y*32;
  int tx = threadIdx.x, ty = threadIdx.y;
  #pragma unroll
  for (int i=ty;i<32;i+=8)
    tile[i][tx] = in[(size_t)(br+i)*768 + bc+tx];
  __syncthreads();
  #pragma unroll
  for (int i=ty;i<32;i+=8)
    o[(size_t)(bc+i)*768 + br+tx] = f2b(tile[tx][i]);
}

__global__ __launch_bounds__(256)
void castX(const float* __restrict__ in, bf16* __restrict__ out)
{
  int i = blockIdx.x*256 + threadIdx.x;
  float4 f = ((const float4*)in)[i];
  union{ unsigned long long u; __bf16 h[4]; } pk;
  pk.h[0]=(__bf16)f.x; pk.h[1]=(__bf16)f.y; pk.h[2]=(__bf16)f.z; pk.h[3]=(__bf16)f.w;
  ((unsigned long long*)out)[i] = pk.u;
}

__global__ void concat_bias(const float* __restrict__ a, const float* __restrict__ b,
                            const float* __restrict__ c, float* __restrict__ o)
{
  int i = blockIdx.x*256 + threadIdx.x;
  if (i < 768) o[i] = a[i];
  else if (i < 1536) o[i] = b[i-768];
  else if (i < 2304) o[i] = c[i-1536];
}

// V part of qkv [row][2304] -> Vt [z=(b,h)][d][s]
__global__ void vtrans(const bf16* __restrict__ v, bf16* __restrict__ vt)
{
  int z = blockIdx.z; int b = z/NHEAD, h = z - b*NHEAD;
  int d0 = blockIdx.x*32, s0 = blockIdx.y*32;
  __shared__ bf16 t[32][33];
  int tx = threadIdx.x, ty = threadIdx.y;
  #pragma unroll
  for (int i=ty;i<32;i+=8)
    t[i][tx] = v[(size_t)(b*SEQ + s0+i)*QKVW + h*HDIM + d0+tx];
  __syncthreads();
  #pragma unroll
  for (int i=ty;i<32;i+=8)
    vt[(size_t)z*HDIM*SEQ + (size_t)(d0+i)*SEQ + s0+tx] = t[tx][i];
}

// ---------------------------------------------------------------------------
// LayerNorm over 768 cols, one block per row. In-place-safe. (unchanged)
// ---------------------------------------------------------------------------
template<typename TO>
__global__ __launch_bounds__(256)
void ln768(const bf16* __restrict__ y, const float* __restrict__ g,
           const float* __restrict__ be, TO* __restrict__ dst)
{
  size_t row = blockIdx.x;
  const bf16* yr = y + row*HID;
  int t = threadIdx.x;
  float x0 = b2f(yr[t]), x1 = b2f(yr[t+256]), x2 = b2f(yr[t+512]);
  float s = x0+x1+x2, q = x0*x0+x1*x1+x2*x2;
  #pragma unroll
  for (int off=32; off; off>>=1){ s += __shfl_xor(s, off); q += __shfl_xor(q, off); }
  __shared__ float rs[4], rq[4];
  int wv = t>>6;
  if ((t&63)==0){ rs[wv]=s; rq[wv]=q; }
  __syncthreads();
  s = rs[0]+rs[1]+rs[2]+rs[3];
  q = rq[0]+rq[1]+rq[2]+rq[3];
  float mean = s*(1.0f/HID);
  float var  = q*(1.0f/HID) - mean*mean;
  float inv  = rsqrtf(var + 1e-12f);
  TO* dr = dst + row*HID;
  stf(dr, t,     (x0-mean)*inv*g[t    ] + be[t    ]);
  stf(dr, t+256, (x1-mean)*inv*g[t+256] + be[t+256]);
  stf(dr, t+512, (x2-mean)*inv*g[t+512] + be[t+512]);
}

// ---------------------------------------------------------------------------
// Dialog (CLS) block: 32 rows total (unchanged)
// ---------------------------------------------------------------------------
__global__ __launch_bounds__(256)
void cls_proj(const bf16* __restrict__ x2,
              const float* __restrict__ Wq, const float* __restrict__ bq,
              const float* __restrict__ Wk, const float* __restrict__ bk,
              const float* __restrict__ Wv, const float* __restrict__ bv,
              bf16* __restrict__ oq, bf16* __restrict__ ok, bf16* __restrict__ ov)
{
  int mat = blockIdx.x, row = blockIdx.y;
  const float* W  = mat==0 ? Wq : (mat==1 ? Wk : Wv);
  const float* bi = mat==0 ? bq : (mat==1 ? bk : bv);
  bf16* out       = mat==0 ? oq : (mat==1 ? ok : ov);
  __shared__ float a[HID];
  const bf16* xr = x2 + (size_t)row*SEQ*HID;
  for (int i=threadIdx.x;i<HID;i+=256) a[i] = b2f(xr[i]);
  __syncthreads();
  for (int c0=0;c0<HID;c0+=256){
    int col = c0 + threadIdx.x;
    float acc = 0.f;
    for (int k=0;k<HID;k++) acc += a[k]*W[(size_t)k*HID + col];
    out[(size_t)row*HID + col] = f2b(acc + bi[col]);
  }
}

__global__ __launch_bounds__(64)
void cls_attn(const bf16* __restrict__ q, const bf16* __restrict__ k,
              const bf16* __restrict__ v, bf16* __restrict__ ctx)
{
  int z = blockIdx.x; int bb = z/NHEAD, h = z - bb*NHEAD;
  __shared__ float P[8][8];
  int t = threadIdx.x;
  int qi = t>>3, ki = t&7;
  float s = 0.f;
  for (int d=0; d<HDIM; d++)
    s += b2f(q[(size_t)(bb*8+qi)*HID + h*HDIM + d]) *
         b2f(k[(size_t)(bb*8+ki)*HID + h*HDIM + d]);
  s = s*0.125f + (ki >= qi ? -10000.0f : 0.0f);
  float m = s;
  #pragma unroll
  for (int off=4; off; off>>=1) m = fmaxf(m, __shfl_xor(m, off, 8));
  float e = __expf(s - m);
  float sum = e;
  #pragma unroll
  for (int off=4; off; off>>=1) sum += __shfl_xor(sum, off, 8);
  P[qi][ki] = e/sum;
  __syncthreads();
  for (int q2=0; q2<8; q2++){
    float acc = 0.f;
    #pragma unroll
    for (int k2=0; k2<8; k2++)
      acc += P[q2][k2] * b2f(v[(size_t)(bb*8+k2)*HID + h*HDIM + t]);
    ctx[(size_t)(bb*8+q2)*HID + h*HDIM + t] = f2b(acc);
  }
}

__global__ __launch_bounds__(256)
void cls_out(const bf16* __restrict__ ctx, const float* __restrict__ Wo,
             const float* __restrict__ bo, const float* __restrict__ g,
             const float* __restrict__ be, bf16* __restrict__ x2)
{
  int row = blockIdx.x;
  __shared__ float a[HID];
  __shared__ float yrow[HID];
  const bf16* cr = ctx + (size_t)row*HID;
  bf16* xr = x2 + (size_t)row*SEQ*HID;
  for (int i=threadIdx.x;i<HID;i+=256) a[i] = b2f(cr[i]);
  __syncthreads();
  for (int c0=0;c0<HID;c0+=256){
    int col = c0 + threadIdx.x;
    float acc = 0.f;
    for (int k=0;k<HID;k++) acc += a[k]*Wo[(size_t)k*HID + col];
    yrow[col] = acc + bo[col] + b2f(xr[col]);
  }
  __syncthreads();
  int t = threadIdx.x;
  float x0 = yrow[t], x1 = yrow[t+256], x2v = yrow[t+512];
  float s = x0+x1+x2v, qq = x0*x0+x1*x1+x2v*x2v;
  #pragma unroll
  for (int off=32; off; off>>=1){ s += __shfl_xor(s, off); qq += __shfl_xor(qq, off); }
  __shared__ float rs[4], rq[4];
  int wv = t>>6;
  if ((t&63)==0){ rs[wv]=s; rq[wv]=qq; }
  __syncthreads();
  s = rs[0]+rs[1]+rs[2]+rs[3];
  qq = rq[0]+rq[1]+rq[2]+rq[3];
  float mean = s*(1.0f/HID);
  float var  = qq*(1.0f/HID) - mean*mean;
  float inv  = rsqrtf(var + 1e-12f);
  xr[t    ] = f2b((x0 -mean)*inv*g[t    ] + be[t    ]);
  xr[t+256] = f2b((x1 -mean)*inv*g[t+256] + be[t+256]);
  xr[t+512] = f2b((x2v-mean)*inv*g[t+512] + be[t+512]);
}

// ---------------------------------------------------------------------------
extern "C" void kernel_launch(void* const* d_in, const int* in_sizes, int n_in,
                              void* d_out, int out_size, void* d_ws, size_t ws_size,
                              hipStream_t stream)
{
  const float* X    = (const float*)d_in[0];
  const float* AM   = (const float*)d_in[1];
  const float* Wq   = (const float*)d_in[2];  const float* bq  = (const float*)d_in[3];
  const float* Wk   = (const float*)d_in[4];  const float* bk  = (const float*)d_in[5];
  const float* Wv   = (const float*)d_in[6];  const float* bv  = (const float*)d_in[7];
  const float* Wao  = (const float*)d_in[8];  const float* bao = (const float*)d_in[9];
  const float* ln1g = (const float*)d_in[10]; const float* ln1b= (const float*)d_in[11];
  const float* dWq  = (const float*)d_in[12]; const float* dbq = (const float*)d_in[13];
  const float* dWk  = (const float*)d_in[14]; const float* dbk = (const float*)d_in[15];
  const float* dWv  = (const float*)d_in[16]; const float* dbv = (const float*)d_in[17];
  const float* dWo  = (const float*)d_in[18]; const float* dbo = (const float*)d_in[19];
  const float* dlng = (const float*)d_in[20]; const float* dlnb= (const float*)d_in[21];
  const float* Wi   = (const float*)d_in[22]; const float* bi  = (const float*)d_in[23];
  const float* Wo2  = (const float*)d_in[24]; const float* bo2 = (const float*)d_in[25];
  const float* ln2g = (const float*)d_in[26]; const float* ln2b= (const float*)d_in[27];
  float* OUT = (float*)d_out;

  char* wp = (char*)d_ws;
  auto alloc = [&](size_t elems)->bf16*{
    bf16* p = (bf16*)wp;
    wp += ((elems*sizeof(bf16) + 255)/256)*256;
    return p;
  };
  bf16* wtq  = alloc(768*768);       // wtq..wtv contiguous => fused QKV B
  bf16* wtk  = alloc(768*768);
  bf16* wtv  = alloc(768*768);
  bf16* wtao = alloc(768*768);
  bf16* wti  = alloc((size_t)768*3072);
  bf16* wto2 = alloc((size_t)3072*768);
  float* bqkv = (float*)alloc(2304*2);
  bf16* qkv  = alloc((size_t)ROWS*QKVW);          // } qkv+vtb contiguous:
  bf16* vtb  = alloc((size_t)ROWS*HID);           // } inter aliases both
  bf16* inter = qkv;
  bf16* scb  = alloc((size_t)ROWS*HID);            // y/x2 slab
  bf16* yb   = scb;
  bf16* x2   = scb;
  bf16* ctxb = alloc((size_t)ROWS*HID);
  bf16* xb   = ctxb;   // bf16 X, dead before flash writes ctxb
  bf16* clsq = alloc(32*HID);
  bf16* clsk = alloc(32*HID);
  bf16* clsv = alloc(32*HID);
  bf16* clsc = alloc(32*HID);
  (void)wtk; (void)wtv;

  dim3 T32(32,8);
  transpose_cast4<<<dim3(24,24,4), T32, 0, stream>>>(Wq, Wk, Wv, Wao, wtq);
  transpose_cast<<<dim3(96,24), T32, 0, stream>>>(Wi,  wti, 768, 3072);
  transpose_cast<<<dim3(24,96), T32, 0, stream>>>(Wo2, wto2,3072, 768);
  concat_bias<<<9,256,0,stream>>>(bq, bk, bv, bqkv);
  castX<<<ROWS*HID/4/256,256,0,stream>>>(X, xb);

  // fused QKV projection: [16384,768] @ [768,2304]^T -> qkv[row][2304]
  gemm8p<0,float><<<dim3(9,64),512,0,stream>>>(
      xb,768,  wtq,768,  qkv,QKVW, 768, bqkv, (const float*)nullptr, 0);

  vtrans<<<dim3(2,16,BATCH*NHEAD), T32, 0, stream>>>(qkv + 1536, vtb);

  // fused flash attention -> ctxb
  flash_attn<<<dim3(NCHUNK, BATCH*NHEAD),256,0,stream>>>(qkv, vtb, AM, ctxb);

  // attn out-proj + bias + residual(X fp32) -> yb ; LN1 in place -> x2
  gemm8p<2,float><<<dim3(3,64),512,0,stream>>>(
      ctxb,768,  wtao,768,  yb,768, 768, bao, X, 768);
  ln768<bf16><<<ROWS,256,0,stream>>>(yb, ln1g, ln1b, x2);

  // dialog (CLS) block on 32 rows
  cls_proj<<<dim3(3,32),256,0,stream>>>(x2, dWq,dbq, dWk,dbk, dWv,dbv,
                                        clsq, clsk, clsv);
  cls_attn<<<48,64,0,stream>>>(clsq, clsk, clsv, clsc);
  cls_out<<<32,256,0,stream>>>(clsc, dWo, dbo, dlng, dlnb, x2);

  // FFN1: inter = gelu(x2 @ Wi + bi)
  gemm8p<1,float><<<dim3(12,64),512,0,stream>>>(
      x2,768,  wti,768,  inter,3072, 768, bi, (const float*)nullptr, 0);
  // FFN2: y = inter @ Wo2 + bo2 + x2
  gemm8p<2,bf16><<<dim3(3,64),512,0,stream>>>(
      inter,3072,  wto2,3072,  yb,768, 3072, bo2, x2, 768);
  ln768<float><<<ROWS,256,0,stream>>>(yb, ln2g, ln2b, OUT);
}

// Round 5
// 822.054 us; speedup vs baseline: 1.0085x; 1.0085x over previous
//
#include <hip/hip_runtime.h>
#include <hip/hip_bf16.h>
#include <math.h>

using bf16 = __hip_bfloat16;
typedef __attribute__((ext_vector_type(8))) __bf16 bf16x8;
typedef __attribute__((ext_vector_type(4))) __bf16 bf16x4;
typedef __attribute__((ext_vector_type(4))) float f32x4;

__device__ __forceinline__ float b2f(bf16 x){ return __bfloat162float(x); }
__device__ __forceinline__ bf16  f2b(float x){ return __float2bfloat16(x); }
__device__ __forceinline__ float ldf(const float* p, size_t i){ return p[i]; }
__device__ __forceinline__ float ldf(const bf16*  p, size_t i){ return b2f(p[i]); }
__device__ __forceinline__ void stf(float* p, size_t i, float v){ p[i] = v; }
__device__ __forceinline__ void stf(bf16*  p, size_t i, float v){ p[i] = f2b(v); }

// vectorized 4-wide store (fp32 / bf16)
__device__ __forceinline__ void st4(float* p, float a, float b, float c, float d){
  float4 f; f.x=a; f.y=b; f.z=c; f.w=d; *(float4*)p = f;
}
__device__ __forceinline__ void st4(bf16* p, float a, float b, float c, float d){
  bf16x4 o; o[0]=(__bf16)a; o[1]=(__bf16)b; o[2]=(__bf16)c; o[3]=(__bf16)d;
  *(bf16x4*)p = o;
}

// fast gelu: tanh form, |err| ~1e-3
__device__ __forceinline__ float gelu_f(float v){
  float u = v*(0.7978845608f + 0.0356774081f*v*v);
  float e = __expf(2.f*u);
  float t = 1.f - 2.f/(e+1.f);          // tanh(u); saturates correctly at +-inf
  return 0.5f*v*(1.f+t);
}

// async 16B global->LDS (LDS base must be wave-uniform; HW adds lane*16)
typedef const __attribute__((address_space(1))) unsigned int* gas_u32p;
typedef __attribute__((address_space(3))) unsigned int* las_u32p;
__device__ __forceinline__ void gl_lds16(const bf16* g, bf16* l){
  __builtin_amdgcn_global_load_lds((gas_u32p)(const void*)g, (las_u32p)(void*)l, 16, 0, 0);
}

#define MFMA16 __builtin_amdgcn_mfma_f32_16x16x32_bf16

// counted LDS wait + scheduler fence (rule #18: fence required after lgkmcnt)
#define LGKM(N) do { \
  asm volatile("s_waitcnt lgkmcnt(" #N ")" ::: "memory"); \
  __builtin_amdgcn_sched_barrier(0); \
} while(0)

#define NHEAD 12
#define HDIM  64
#define HID   768
#define SEQ   512
#define BATCH 32
#define ROWS  (BATCH*SEQ)   // 16384
#define QKVW  2304          // packed qkv row width
#define QCH   128           // q-chunk rows for attention
#define NCHUNK (SEQ/QCH)    // 4
#define FT    128           // flash key tile

// ---------------------------------------------------------------------------
// 256x256 8-phase MFMA GEMM (T2+T3+T4+T5): C[M,N] = A[M,K]*Bt[N,K]^T +bias.
// (unchanged from round 3: counted lgkmcnt chunked MFMA, 1 barrier/phase)
// ---------------------------------------------------------------------------
template<int EPI, typename TR>
__global__ __launch_bounds__(512,2)
void gemm8p(const bf16* __restrict__ A, int lda,
            const bf16* __restrict__ Bt, int ldb,
            bf16* __restrict__ C, int ldc, int K,
            const float* __restrict__ bias,
            const TR* __restrict__ res, int ldres)
{
  __shared__ __align__(16) bf16 tileLds[4][256*64];   // [buf*2 + (0=A,1=B)]

  const int tid  = threadIdx.x;
  const int wave = tid>>6, lane = tid&63;
  const int r = lane&15, qd = lane>>4;
  const int wr = wave>>2, wc = wave&3;        // 2M x 4N waves
  const int m0 = blockIdx.y*256, n0 = blockIdx.x*256;
  const int NTK = K>>6;
  const int wbase = wave*512;                 // per-wave LDS element base

  const int sr = tid>>3, sp = tid&7;
  const bf16* pA = A  + (size_t)(m0+sr)*lda + ((sp^(sr&7))<<3);
  const bf16* pB = Bt + (size_t)(n0+sr)*ldb + ((sp^(sr&7))<<3);

  auto stage = [&](int H){
    const int u = H>>2, idx = H&3, bufi = u&1;
    const size_t kof = (size_t)u*64;
    if (idx==0){            // A half0
      gl_lds16(pA + kof,                    tileLds[bufi*2] + wbase);
      gl_lds16(pA + kof + (size_t)64*lda,   tileLds[bufi*2] + wbase + 4096);
    } else if (idx==3){     // A half1
      gl_lds16(pA + kof + (size_t)128*lda,  tileLds[bufi*2] + 8192 + wbase);
      gl_lds16(pA + kof + (size_t)192*lda,  tileLds[bufi*2] + 8192 + wbase + 4096);
    } else {                // B half (idx1->h0, idx2->h1)
      const int h = idx-1;
      gl_lds16(pB + kof + (size_t)(h*128)*ldb,
               tileLds[bufi*2+1] + h*8192 + wbase);
      gl_lds16(pB + kof + (size_t)(h*128+64)*ldb,
               tileLds[bufi*2+1] + h*8192 + wbase + 4096);
    }
  };

  auto rdA = [&](const bf16* base, int mi, int ks)->bf16x8{
    const int row = mi*32 + wr*16 + r;
    return *(const bf16x8*)(base + row*64 + ((((ks<<2)|qd) ^ (r&7))<<3));
  };
  auto rdB = [&](const bf16* base, int nj, int ks)->bf16x8{
    const int row = nj*64 + wc*16 + r;
    return *(const bf16x8*)(base + row*64 + ((((ks<<2)|qd) ^ (r&7))<<3));
  };

  #pragma unroll
  for (int H=0; H<7; ++H) stage(H);
  asm volatile("s_waitcnt vmcnt(6)" ::: "memory");
  __builtin_amdgcn_s_barrier();

  f32x4 acc[8][4] = {};

  for (int t=0; t<NTK; ++t){
    const bf16* a = tileLds[(t&1)*2];
    const bf16* b = tileLds[(t&1)*2+1];
    const int Hb = 4*t + 6;
    const int Hmax = 4*NTK;
    bf16x8 af[4][2], bn0[2][2], bn1[2][2];

    // ---- phase 1: quadrant (m0,n0); 12 reads; stage (t+1) A1
    af[0][0]=rdA(a,0,0); af[0][1]=rdA(a,0,1);
    af[1][0]=rdA(a,1,0); af[1][1]=rdA(a,1,1);
    bn0[0][0]=rdB(b,0,0); bn0[0][1]=rdB(b,0,1);
    bn0[1][0]=rdB(b,1,0); bn0[1][1]=rdB(b,1,1);
    __builtin_amdgcn_sched_barrier(0);
    af[2][0]=rdA(a,2,0); af[2][1]=rdA(a,2,1);
    af[3][0]=rdA(a,3,0); af[3][1]=rdA(a,3,1);
    if (Hb+1 < Hmax) stage(Hb+1);
    LGKM(4);                               // first 8 reads landed
    __builtin_amdgcn_s_setprio(1);
    #pragma unroll
    for (int mi=0;mi<2;mi++)
      #pragma unroll
      for (int nj=0;nj<2;nj++){
        acc[mi][nj] = MFMA16(af[mi][0], bn0[nj][0], acc[mi][nj],0,0,0);
        acc[mi][nj] = MFMA16(af[mi][1], bn0[nj][1], acc[mi][nj],0,0,0);
      }
    LGKM(0);                               // af[2..3] landed
    #pragma unroll
    for (int mi=2;mi<4;mi++)
      #pragma unroll
      for (int nj=0;nj<2;nj++){
        acc[mi][nj] = MFMA16(af[mi][0], bn0[nj][0], acc[mi][nj],0,0,0);
        acc[mi][nj] = MFMA16(af[mi][1], bn0[nj][1], acc[mi][nj],0,0,0);
      }
    __builtin_amdgcn_s_setprio(0);
    __builtin_amdgcn_s_barrier();

    // ---- phase 2: quadrant (m0,n1); 4 reads; stage (t+2) A0
    bn1[0][0]=rdB(b,2,0); bn1[0][1]=rdB(b,2,1);
    __builtin_amdgcn_sched_barrier(0);
    bn1[1][0]=rdB(b,3,0); bn1[1][1]=rdB(b,3,1);
    if (Hb+2 < Hmax) stage(Hb+2);
    LGKM(2);
    __builtin_amdgcn_s_setprio(1);
    #pragma unroll
    for (int mi=0;mi<4;mi++){
      acc[mi][2] = MFMA16(af[mi][0], bn1[0][0], acc[mi][2],0,0,0);
      acc[mi][2] = MFMA16(af[mi][1], bn1[0][1], acc[mi][2],0,0,0);
    }
    LGKM(0);
    #pragma unroll
    for (int mi=0;mi<4;mi++){
      acc[mi][3] = MFMA16(af[mi][0], bn1[1][0], acc[mi][3],0,0,0);
      acc[mi][3] = MFMA16(af[mi][1], bn1[1][1], acc[mi][3],0,0,0);
    }
    __builtin_amdgcn_s_setprio(0);
    __builtin_amdgcn_s_barrier();

    // ---- phase 3: quadrant (m1,n1); 8 reads (af := m1); stage (t+2) B0
    af[0][0]=rdA(a,4,0); af[0][1]=rdA(a,4,1);
    af[1][0]=rdA(a,5,0); af[1][1]=rdA(a,5,1);
    __builtin_amdgcn_sched_barrier(0);
    af[2][0]=rdA(a,6,0); af[2][1]=rdA(a,6,1);
    af[3][0]=rdA(a,7,0); af[3][1]=rdA(a,7,1);
    if (Hb+3 < Hmax) stage(Hb+3);
    LGKM(4);
    __builtin_amdgcn_s_setprio(1);
    #pragma unroll
    for (int mi=0;mi<2;mi++)
      #pragma unroll
      for (int nj=0;nj<2;nj++){
        acc[4+mi][2+nj] = MFMA16(af[mi][0], bn1[nj][0], acc[4+mi][2+nj],0,0,0);
        acc[4+mi][2+nj] = MFMA16(af[mi][1], bn1[nj][1], acc[4+mi][2+nj],0,0,0);
      }
    LGKM(0);
    #pragma unroll
    for (int mi=2;mi<4;mi++)
      #pragma unroll
      for (int nj=0;nj<2;nj++){
        acc[4+mi][2+nj] = MFMA16(af[mi][0], bn1[nj][0], acc[4+mi][2+nj],0,0,0);
        acc[4+mi][2+nj] = MFMA16(af[mi][1], bn1[nj][1], acc[4+mi][2+nj],0,0,0);
      }
    __builtin_amdgcn_s_setprio(0);
    __builtin_amdgcn_s_barrier();

    // ---- phase 4: quadrant (m1,n0); 0 reads (af=m1, bn0 live); stage (t+2) B1
    if (Hb+4 < Hmax) stage(Hb+4);
    __builtin_amdgcn_s_setprio(1);
    #pragma unroll
    for (int mi=0;mi<4;mi++)
      #pragma unroll
      for (int nj=0;nj<2;nj++){
        acc[4+mi][nj] = MFMA16(af[mi][0], bn0[nj][0], acc[4+mi][nj],0,0,0);
        acc[4+mi][nj] = MFMA16(af[mi][1], bn0[nj][1], acc[4+mi][nj],0,0,0);
      }
    __builtin_amdgcn_s_setprio(0);
    if (t < NTK-2) { asm volatile("s_waitcnt vmcnt(6)" ::: "memory"); }
    else           { asm volatile("s_waitcnt vmcnt(0)" ::: "memory"); }
    __builtin_amdgcn_s_barrier();
  }

  // epilogue
  float bs[4];
  #pragma unroll
  for (int nj=0;nj<4;nj++)
    bs[nj] = bias ? bias[n0 + nj*64 + wc*16 + r] : 0.f;
  #pragma unroll
  for (int mi=0;mi<8;mi++){
    #pragma unroll
    for (int nj=0;nj<4;nj++){
      #pragma unroll
      for (int i=0;i<4;i++){
        const int mm = m0 + mi*32 + wr*16 + qd*4 + i;
        const int nn = n0 + nj*64 + wc*16 + r;
        float v = acc[mi][nj][i] + bs[nj];
        if (EPI==1) v = gelu_f(v);
        if (EPI==2) v += ldf(res, (size_t)mm*ldres + nn);
        C[(size_t)mm*ldc + nn] = f2b(v);
      }
    }
  }
}

// ---------------------------------------------------------------------------
// Fused flash attention v2b: round-4 structure (3 barriers/tile, Q in regs,
// separate Ps, mask in regs) but softmax back in NATURAL exp domain.
// Round-4 regression diagnosis: exp2f lowers to the __ocml_exp2_f32 libcall
// (range/denormal handling, ~4x the VALU ops of __expf's v_mul+v_exp) and
// softmax issues 72 exp calls/lane/tile -> +30% VALUBusy, +12us. __expf is
// the known-good fast path (round 3). This round isolates that variable.
// LDS: Ks 16K + Vts 16K + Ps 16K = 48KB -> 3 blocks/CU.
// ---------------------------------------------------------------------------
__global__ __launch_bounds__(256)
void flash_attn(const bf16* __restrict__ qkv, const bf16* __restrict__ vtb,
                const float* __restrict__ mask, bf16* __restrict__ ctx)
{
  const int qc = blockIdx.x;
  const int z  = blockIdx.y;
  const int b  = z / NHEAD, h = z - b*NHEAD;
  const int q0 = qc*QCH;

  __shared__ __align__(16) bf16 Ks[FT*64];
  __shared__ __align__(16) bf16 Vts[64*FT];
  __shared__ __align__(16) bf16 Ps[QCH*64];

  const int tid = threadIdx.x;
  const int wave = tid>>6, lane = tid&63;
  const int r = lane&15, qd = lane>>4;
  const int wr = wave;                        // wave owns q-rows wr*32..+32

  const bf16* Qg = qkv + ((size_t)(b*SEQ + q0))*QKVW + h*HDIM;
  const bf16* Kg = qkv + ((size_t)b*SEQ)*QKVW + 768 + h*HDIM;
  const bf16* Vg = vtb + (size_t)z*HDIM*SEQ;

  auto stageK = [&](int k0){
    #pragma unroll
    for (int c0=0;c0<1024;c0+=256){          // K tile 128 rows x 8 chunks
      int c = c0+tid, row = c>>3, pos = c&7;
      gl_lds16(Kg + (size_t)(k0+row)*QKVW + ((pos^(row&7))*8),
               Ks + (size_t)(c0 + wave*64)*8);
    }
  };
  auto stageV = [&](int k0){
    #pragma unroll
    for (int c0=0;c0<1024;c0+=256){          // Vt tile 64 rows x 16 chunks
      int c = c0+tid, row = c>>4, pos = c&15;
      gl_lds16(Vg + (size_t)row*SEQ + k0 + ((pos^(row&7))*8),
               Vts + (size_t)(c0 + wave*64)*8);
    }
  };

  // prologue: stage tile 0, Q -> registers (fragment layout, no swizzle)
  stageK(0);
  stageV(0);
  bf16x8 qf[2][2];
  #pragma unroll
  for (int mi=0;mi<2;mi++)
    #pragma unroll
    for (int ks=0;ks<2;ks++)
      qf[mi][ks] = *(const bf16x8*)(Qg + (size_t)(wr*32+mi*16+r)*QKVW + (ks*4+qd)*8);

  f32x4 accO[2][4] = {};             // rows wr*32+mi*16+qd*4+i ; col d=ni*16+r
  float mrun[2][4], lrun[2][4];
  #pragma unroll
  for (int a=0;a<2;a++)
    #pragma unroll
    for (int i2=0;i2<4;i2++){ mrun[a][i2]=-1e30f; lrun[a][i2]=0.f; }

  for (int k0=0; k0<SEQ; k0+=FT){
    __syncthreads();                 // K(t),V(t) landed (vmcnt0 in syncthreads)

    // mask for this tile -> regs (L2/L3-resident; consumed in softmax)
    float mk[8];
    #pragma unroll
    for (int ni=0;ni<8;ni++)
      mk[ni] = mask[(size_t)b*SEQ + k0 + ni*16 + r];

    // S = Q K^T : this wave M=32, N=128, K=64 (Q in regs, K from LDS)
    f32x4 accS[2][8] = {};
    #pragma unroll
    for (int ks=0; ks<2; ks++){
      bf16x8 bfv[8];
      #pragma unroll
      for (int ni=0;ni<8;ni++){
        int row = ni*16 + r;
        int jr = ks*4 + qd;
        bfv[ni] = *(const bf16x8*)(Ks + row*64 + ((jr^(row&7))*8));
      }
      #pragma unroll
      for (int mi=0;mi<2;mi++)
        #pragma unroll
        for (int ni=0;ni<8;ni++)
          accS[mi][ni] = MFMA16(qf[mi][ks], bfv[ni], accS[mi][ni], 0,0,0);
    }

    __syncthreads();                 // barrier A: all waves done reading Ks
    if (k0+FT < SEQ) stageK(k0+FT);  // K(t+1) flies under softmax+PV

    // online softmax (natural domain, __expf = v_mul+v_exp fast path)
    #pragma unroll
    for (int mi=0;mi<2;mi++){
      #pragma unroll
      for (int i=0;i<4;i++){
        float mx = -1e30f;
        #pragma unroll
        for (int ni=0;ni<8;ni++){
          float v = accS[mi][ni][i]*0.125f + mk[ni];
          accS[mi][ni][i] = v;
          mx = fmaxf(mx, v);
        }
        #pragma unroll
        for (int off=1; off<16; off<<=1) mx = fmaxf(mx, __shfl_xor(mx, off));
        float mnew = fmaxf(mrun[mi][i], mx);
        float alpha = __expf(mrun[mi][i] - mnew);
        mrun[mi][i] = mnew;
        float ssum = 0.f;
        #pragma unroll
        for (int ni=0;ni<8;ni++){
          float p = __expf(accS[mi][ni][i] - mnew);
          accS[mi][ni][i] = p;
          ssum += p;
        }
        #pragma unroll
        for (int off=1; off<16; off<<=1) ssum += __shfl_xor(ssum, off);
        lrun[mi][i] = lrun[mi][i]*alpha + ssum;
        #pragma unroll
        for (int ni=0;ni<4;ni++) accO[mi][ni][i] *= alpha;
      }
    }

    // P -> Ps (own rows; separate buffer => wave-local, lgkm-ordered), 2 halves
    #pragma unroll
    for (int half=0; half<2; half++){
      #pragma unroll
      for (int mi=0;mi<2;mi++){
        #pragma unroll
        for (int i=0;i<4;i++){
          int row = wr*32 + mi*16 + qd*4 + i;
          #pragma unroll
          for (int nj=0;nj<4;nj++){
            int colL = nj*16 + r;
            int chunk = colL>>3;
            Ps[row*64 + ((chunk^(row&7))*8) + (colL&7)] = f2b(accS[mi][half*4+nj][i]);
          }
        }
      }
      // PV: O += P[half] * V[half]  (Ps own rows; Vts stable this tile)
      #pragma unroll
      for (int ks=0; ks<2; ks++){
        bf16x8 af[2], bfv[4];
        #pragma unroll
        for (int mi=0;mi<2;mi++){
          int row = wr*32 + mi*16 + r;
          int jr = ks*4 + qd;
          af[mi] = *(const bf16x8*)(Ps + row*64 + ((jr^(row&7))*8));
        }
        #pragma unroll
        for (int ni=0;ni<4;ni++){
          int row = ni*16 + r;
          int jrv = half*8 + ks*4 + qd;
          bfv[ni] = *(const bf16x8*)(Vts + row*FT + ((jrv^(row&7))*8));
        }
        #pragma unroll
        for (int mi=0;mi<2;mi++)
          #pragma unroll
          for (int ni=0;ni<4;ni++)
            accO[mi][ni] = MFMA16(af[mi], bfv[ni], accO[mi][ni], 0,0,0);
      }
    }

    __syncthreads();                 // barrier B: all waves done reading Vts
    if (k0+FT < SEQ) stageV(k0+FT);  // V(t+1); drained at next loop-top sync
  }

  bf16* Cg = ctx + ((size_t)(b*SEQ + q0))*HID + h*HDIM;
  #pragma unroll
  for (int mi=0;mi<2;mi++)
    #pragma unroll
    for (int i=0;i<4;i++){
      int row = wr*32 + mi*16 + qd*4 + i;
      float invl = 1.0f/lrun[mi][i];
      #pragma unroll
      for (int ni=0;ni<4;ni++)
        Cg[(size_t)row*HID + ni*16 + r] = f2b(accO[mi][ni][i]*invl);
    }
}

// ---------------------------------------------------------------------------
// Weight transpose + fp32->bf16 cast (unchanged)
// ---------------------------------------------------------------------------
__global__ void transpose_cast(const float* __restrict__ in, bf16* __restrict__ out,
                               int R, int C)
{
  __shared__ float tile[32][33];
  int bc = blockIdx.x*32, br = blockIdx.y*32;
  int tx = threadIdx.x, ty = threadIdx.y;
  #pragma unroll
  for (int i=ty;i<32;i+=8)
    tile[i][tx] = in[(size_t)(br+i)*C + bc+tx];
  __syncthreads();
  #pragma unroll
  for (int i=ty;i<32;i+=8)
    out[(size_t)(bc+i)*R + br+tx] = f2b(tile[tx][i]);
}

__global__ void transpose_cast4(const float* __restrict__ w0, const float* __restrict__ w1,
                                const float* __restrict__ w2, const float* __restrict__ w3,
                                bf16* __restrict__ out)
{
  const float* in = blockIdx.z==0?w0 : blockIdx.z==1?w1 : blockIdx.z==2?w2 : w3;
  bf16* o = out + (size_t)blockIdx.z*768*768;
  __shared__ float tile[32][33];
  int bc = blockIdx.x*32, br = blockIdx.y*32;
  int tx = threadIdx.x, ty = threadIdx.y;
  #pragma unroll
  for (int i=ty;i<32;i+=8)
    tile[i][tx] = in[(size_t)(br+i)*768 + bc+tx];
  __syncthreads();
  #pragma unroll
  for (int i=ty;i<32;i+=8)
    o[(size_t)(bc+i)*768 + br+tx] = f2b(tile[tx][i]);
}

__global__ __launch_bounds__(256)
void castX(const float* __restrict__ in, bf16* __restrict__ out)
{
  int i = blockIdx.x*256 + threadIdx.x;
  float4 f = ((const float4*)in)[i];
  union{ unsigned long long u; __bf16 h[4]; } pk;
  pk.h[0]=(__bf16)f.x; pk.h[1]=(__bf16)f.y; pk.h[2]=(__bf16)f.z; pk.h[3]=(__bf16)f.w;
  ((unsigned long long*)out)[i] = pk.u;
}

__global__ void concat_bias(const float* __restrict__ a, const float* __restrict__ b,
                            const float* __restrict__ c, float* __restrict__ o)
{
  int i = blockIdx.x*256 + threadIdx.x;
  if (i < 768) o[i] = a[i];
  else if (i < 1536) o[i] = b[i-768];
  else if (i < 2304) o[i] = c[i-1536];
}

// V part of qkv [row][2304] -> Vt [z=(b,h)][d][s]
__global__ void vtrans(const bf16* __restrict__ v, bf16* __restrict__ vt)
{
  int z = blockIdx.z; int b = z/NHEAD, h = z - b*NHEAD;
  int d0 = blockIdx.x*32, s0 = blockIdx.y*32;
  __shared__ bf16 t[32][33];
  int tx = threadIdx.x, ty = threadIdx.y;
  #pragma unroll
  for (int i=ty;i<32;i+=8)
    t[i][tx] = v[(size_t)(b*SEQ + s0+i)*QKVW + h*HDIM + d0+tx];
  __syncthreads();
  #pragma unroll
  for (int i=ty;i<32;i+=8)
    vt[(size_t)z*HDIM*SEQ + (size_t)(d0+i)*SEQ + s0+tx] = t[tx][i];
}

// ---------------------------------------------------------------------------
// LayerNorm over 768 cols: ONE WAVE per row (v2). bf16x4/float4 vectorized
// loads+stores, pure-shfl reduce, no LDS, no syncthreads. 4 rows/block.
// ---------------------------------------------------------------------------
template<typename TO>
__global__ __launch_bounds__(256)
void ln768(const bf16* __restrict__ y, const float* __restrict__ g,
           const float* __restrict__ be, TO* __restrict__ dst)
{
  const int wave = threadIdx.x>>6, lane = threadIdx.x&63;
  const size_t row = (size_t)blockIdx.x*4 + wave;
  const bf16* yr = y + row*HID;
  float x[12];
  float s = 0.f, q = 0.f;
  #pragma unroll
  for (int c=0;c<3;c++){
    bf16x4 v = *(const bf16x4*)(yr + c*256 + lane*4);
    #pragma unroll
    for (int j=0;j<4;j++){
      float f = (float)v[j];
      x[c*4+j] = f;
      s += f; q += f*f;
    }
  }
  #pragma unroll
  for (int off=1; off<64; off<<=1){ s += __shfl_xor(s, off); q += __shfl_xor(q, off); }
  float mean = s*(1.0f/HID);
  float var  = q*(1.0f/HID) - mean*mean;
  float inv  = rsqrtf(var + 1e-12f);
  TO* dr = dst + row*HID;
  #pragma unroll
  for (int c=0;c<3;c++){
    float4 gg = *(const float4*)(g  + c*256 + lane*4);
    float4 bb = *(const float4*)(be + c*256 + lane*4);
    st4(dr + c*256 + lane*4,
        (x[c*4+0]-mean)*inv*gg.x + bb.x,
        (x[c*4+1]-mean)*inv*gg.y + bb.y,
        (x[c*4+2]-mean)*inv*gg.z + bb.z,
        (x[c*4+3]-mean)*inv*gg.w + bb.w);
  }
}

// ---------------------------------------------------------------------------
// Dialog (CLS) block: 32 rows total (unchanged)
// ---------------------------------------------------------------------------
__global__ __launch_bounds__(256)
void cls_proj(const bf16* __restrict__ x2,
              const float* __restrict__ Wq, const float* __restrict__ bq,
              const float* __restrict__ Wk, const float* __restrict__ bk,
              const float* __restrict__ Wv, const float* __restrict__ bv,
              bf16* __restrict__ oq, bf16* __restrict__ ok, bf16* __restrict__ ov)
{
  int mat = blockIdx.x, row = blockIdx.y;
  const float* W  = mat==0 ? Wq : (mat==1 ? Wk : Wv);
  const float* bi = mat==0 ? bq : (mat==1 ? bk : bv);
  bf16* out       = mat==0 ? oq : (mat==1 ? ok : ov);
  __shared__ float a[HID];
  const bf16* xr = x2 + (size_t)row*SEQ*HID;
  for (int i=threadIdx.x;i<HID;i+=256) a[i] = b2f(xr[i]);
  __syncthreads();
  for (int c0=0;c0<HID;c0+=256){
    int col = c0 + threadIdx.x;
    float acc = 0.f;
    for (int k=0;k<HID;k++) acc += a[k]*W[(size_t)k*HID + col];
    out[(size_t)row*HID + col] = f2b(acc + bi[col]);
  }
}

__global__ __launch_bounds__(64)
void cls_attn(const bf16* __restrict__ q, const bf16* __restrict__ k,
              const bf16* __restrict__ v, bf16* __restrict__ ctx)
{
  int z = blockIdx.x; int bb = z/NHEAD, h = z - bb*NHEAD;
  __shared__ float P[8][8];
  int t = threadIdx.x;
  int qi = t>>3, ki = t&7;
  float s = 0.f;
  for (int d=0; d<HDIM; d++)
    s += b2f(q[(size_t)(bb*8+qi)*HID + h*HDIM + d]) *
         b2f(k[(size_t)(bb*8+ki)*HID + h*HDIM + d]);
  s = s*0.125f + (ki >= qi ? -10000.0f : 0.0f);
  float m = s;
  #pragma unroll
  for (int off=4; off; off>>=1) m = fmaxf(m, __shfl_xor(m, off, 8));
  float e = __expf(s - m);
  float sum = e;
  #pragma unroll
  for (int off=4; off; off>>=1) sum += __shfl_xor(sum, off, 8);
  P[qi][ki] = e/sum;
  __syncthreads();
  for (int q2=0; q2<8; q2++){
    float acc = 0.f;
    #pragma unroll
    for (int k2=0; k2<8; k2++)
      acc += P[q2][k2] * b2f(v[(size_t)(bb*8+k2)*HID + h*HDIM + t]);
    ctx[(size_t)(bb*8+q2)*HID + h*HDIM + t] = f2b(acc);
  }
}

__global__ __launch_bounds__(256)
void cls_out(const bf16* __restrict__ ctx, const float* __restrict__ Wo,
             const float* __restrict__ bo, const float* __restrict__ g,
             const float* __restrict__ be, bf16* __restrict__ x2)
{
  int row = blockIdx.x;
  __shared__ float a[HID];
  __shared__ float yrow[HID];
  const bf16* cr = ctx + (size_t)row*HID;
  bf16* xr = x2 + (size_t)row*SEQ*HID;
  for (int i=threadIdx.x;i<HID;i+=256) a[i] = b2f(cr[i]);
  __syncthreads();
  for (int c0=0;c0<HID;c0+=256){
    int col = c0 + threadIdx.x;
    float acc = 0.f;
    for (int k=0;k<HID;k++) acc += a[k]*Wo[(size_t)k*HID + col];
    yrow[col] = acc + bo[col] + b2f(xr[col]);
  }
  __syncthreads();
  int t = threadIdx.x;
  float x0 = yrow[t], x1 = yrow[t+256], x2v = yrow[t+512];
  float s = x0+x1+x2v, qq = x0*x0+x1*x1+x2v*x2v;
  #pragma unroll
  for (int off=32; off; off>>=1){ s += __shfl_xor(s, off); qq += __shfl_xor(qq, off); }
  __shared__ float rs[4], rq[4];
  int wv = t>>6;
  if ((t&63)==0){ rs[wv]=s; rq[wv]=qq; }
  __syncthreads();
  s = rs[0]+rs[1]+rs[2]+rs[3];
  qq = rq[0]+rq[1]+rq[2]+rq[3];
  float mean = s*(1.0f/HID);
  float var  = qq*(1.0f/HID) - mean*mean;
  float inv  = rsqrtf(var + 1e-12f);
  xr[t    ] = f2b((x0 -mean)*inv*g[t    ] + be[t    ]);
  xr[t+256] = f2b((x1 -mean)*inv*g[t+256] + be[t+256]);
  xr[t+512] = f2b((x2v-mean)*inv*g[t+512] + be[t+512]);
}

// ---------------------------------------------------------------------------
extern "C" void kernel_launch(void* const* d_in, const int* in_sizes, int n_in,
                              void* d_out, int out_size, void* d_ws, size_t ws_size,
                              hipStream_t stream)
{
  const float* X    = (const float*)d_in[0];
  const float* AM   = (const float*)d_in[1];
  const float* Wq   = (const float*)d_in[2];  const float* bq  = (const float*)d_in[3];
  const float* Wk   = (const float*)d_in[4];  const float* bk  = (const float*)d_in[5];
  const float* Wv   = (const float*)d_in[6];  const float* bv  = (const float*)d_in[7];
  const float* Wao  = (const float*)d_in[8];  const float* bao = (const float*)d_in[9];
  const float* ln1g = (const float*)d_in[10]; const float* ln1b= (const float*)d_in[11];
  const float* dWq  = (const float*)d_in[12]; const float* dbq = (const float*)d_in[13];
  const float* dWk  = (const float*)d_in[14]; const float* dbk = (const float*)d_in[15];
  const float* dWv  = (const float*)d_in[16]; const float* dbv = (const float*)d_in[17];
  const float* dWo  = (const float*)d_in[18]; const float* dbo = (const float*)d_in[19];
  const float* dlng = (const float*)d_in[20]; const float* dlnb= (const float*)d_in[21];
  const float* Wi   = (const float*)d_in[22]; const float* bi  = (const float*)d_in[23];
  const float* Wo2  = (const float*)d_in[24]; const float* bo2 = (const float*)d_in[25];
  const float* ln2g = (const float*)d_in[26]; const float* ln2b= (const float*)d_in[27];
  float* OUT = (float*)d_out;

  char* wp = (char*)d_ws;
  auto alloc = [&](size_t elems)->bf16*{
    bf16* p = (bf16*)wp;
    wp += ((elems*sizeof(bf16) + 255)/256)*256;
    return p;
  };
  bf16* wtq  = alloc(768*768);       // wtq..wtv contiguous => fused QKV B
  bf16* wtk  = alloc(768*768);
  bf16* wtv  = alloc(768*768);
  bf16* wtao = alloc(768*768);
  bf16* wti  = alloc((size_t)768*3072);
  bf16* wto2 = alloc((size_t)3072*768);
  float* bqkv = (float*)alloc(2304*2);
  bf16* qkv  = alloc((size_t)ROWS*QKVW);          // } qkv+vtb contiguous:
  bf16* vtb  = alloc((size_t)ROWS*HID);           // } inter aliases both
  bf16* inter = qkv;
  bf16* scb  = alloc((size_t)ROWS*HID);            // y/x2 slab
  bf16* yb   = scb;
  bf16* x2   = scb;
  bf16* ctxb = alloc((size_t)ROWS*HID);
  bf16* xb   = ctxb;   // bf16 X, dead before flash writes ctxb
  bf16* clsq = alloc(32*HID);
  bf16* clsk = alloc(32*HID);
  bf16* clsv = alloc(32*HID);
  bf16* clsc = alloc(32*HID);
  (void)wtk; (void)wtv;

  dim3 T32(32,8);
  transpose_cast4<<<dim3(24,24,4), T32, 0, stream>>>(Wq, Wk, Wv, Wao, wtq);
  transpose_cast<<<dim3(96,24), T32, 0, stream>>>(Wi,  wti, 768, 3072);
  transpose_cast<<<dim3(24,96), T32, 0, stream>>>(Wo2, wto2,3072, 768);
  concat_bias<<<9,256,0,stream>>>(bq, bk, bv, bqkv);
  castX<<<ROWS*HID/4/256,256,0,stream>>>(X, xb);

  // fused QKV projection: [16384,768] @ [768,2304]^T -> qkv[row][2304]
  gemm8p<0,float><<<dim3(9,64),512,0,stream>>>(
      xb,768,  wtq,768,  qkv,QKVW, 768, bqkv, (const float*)nullptr, 0);

  vtrans<<<dim3(2,16,BATCH*NHEAD), T32, 0, stream>>>(qkv + 1536, vtb);

  // fused flash attention -> ctxb
  flash_attn<<<dim3(NCHUNK, BATCH*NHEAD),256,0,stream>>>(qkv, vtb, AM, ctxb);

  // attn out-proj + bias + residual(X fp32) -> yb ; LN1 in place -> x2
  gemm8p<2,float><<<dim3(3,64),512,0,stream>>>(
      ctxb,768,  wtao,768,  yb,768, 768, bao, X, 768);
  ln768<bf16><<<ROWS/4,256,0,stream>>>(yb, ln1g, ln1b, x2);

  // dialog (CLS) block on 32 rows
  cls_proj<<<dim3(3,32),256,0,stream>>>(x2, dWq,dbq, dWk,dbk, dWv,dbv,
                                        clsq, clsk, clsv);
  cls_attn<<<48,64,0,stream>>>(clsq, clsk, clsv, clsc);
  cls_out<<<32,256,0,stream>>>(clsc, dWo, dbo, dlng, dlnb, x2);

  // FFN1: inter = gelu(x2 @ Wi + bi)
  gemm8p<1,float><<<dim3(12,64),512,0,stream>>>(
      x2,768,  wti,768,  inter,3072, 768, bi, (const float*)nullptr, 0);
  // FFN2: y = inter @ Wo2 + bo2 + x2
  gemm8p<2,bf16><<<dim3(3,64),512,0,stream>>>(
      inter,3072,  wto2,3072,  yb,768, 3072, bo2, x2, 768);
  ln768<float><<<ROWS/4,256,0,stream>>>(yb, ln2g, ln2b, OUT);
}

// Round 6
// 813.117 us; speedup vs baseline: 1.0196x; 1.0110x over previous
//
#include <hip/hip_runtime.h>
#include <hip/hip_bf16.h>
#include <math.h>

using bf16 = __hip_bfloat16;
typedef __attribute__((ext_vector_type(8))) __bf16 bf16x8;
typedef __attribute__((ext_vector_type(4))) __bf16 bf16x4;
typedef __attribute__((ext_vector_type(4))) float f32x4;
typedef __attribute__((ext_vector_type(16))) float f32x16;
typedef unsigned int u32x2 __attribute__((ext_vector_type(2)));

__device__ __forceinline__ float b2f(bf16 x){ return __bfloat162float(x); }
__device__ __forceinline__ bf16  f2b(float x){ return __float2bfloat16(x); }
__device__ __forceinline__ float ldf(const float* p, size_t i){ return p[i]; }
__device__ __forceinline__ float ldf(const bf16*  p, size_t i){ return b2f(p[i]); }
__device__ __forceinline__ void stf(float* p, size_t i, float v){ p[i] = v; }
__device__ __forceinline__ void stf(bf16*  p, size_t i, float v){ p[i] = f2b(v); }

// vectorized 4-wide store (fp32 / bf16)
__device__ __forceinline__ void st4(float* p, float a, float b, float c, float d){
  float4 f; f.x=a; f.y=b; f.z=c; f.w=d; *(float4*)p = f;
}
__device__ __forceinline__ void st4(bf16* p, float a, float b, float c, float d){
  bf16x4 o; o[0]=(__bf16)a; o[1]=(__bf16)b; o[2]=(__bf16)c; o[3]=(__bf16)d;
  *(bf16x4*)p = o;
}

// fast gelu: tanh form, |err| ~1e-3
__device__ __forceinline__ float gelu_f(float v){
  float u = v*(0.7978845608f + 0.0356774081f*v*v);
  float e = __expf(2.f*u);
  float t = 1.f - 2.f/(e+1.f);          // tanh(u); saturates correctly at +-inf
  return 0.5f*v*(1.f+t);
}

// async 16B global->LDS (LDS base must be wave-uniform; HW adds lane*16)
typedef const __attribute__((address_space(1))) unsigned int* gas_u32p;
typedef __attribute__((address_space(3))) unsigned int* las_u32p;
__device__ __forceinline__ void gl_lds16(const bf16* g, bf16* l){
  __builtin_amdgcn_global_load_lds((gas_u32p)(const void*)g, (las_u32p)(void*)l, 16, 0, 0);
}

#define MFMA16 __builtin_amdgcn_mfma_f32_16x16x32_bf16
#define MFMA32 __builtin_amdgcn_mfma_f32_32x32x16_bf16

// counted LDS wait + scheduler fence (rule #18: fence required after lgkmcnt)
#define LGKM(N) do { \
  asm volatile("s_waitcnt lgkmcnt(" #N ")" ::: "memory"); \
  __builtin_amdgcn_sched_barrier(0); \
} while(0)

// pack 2 f32 -> 1 u32 of 2 bf16 (T12 recipe; no builtin on gfx950)
__device__ __forceinline__ unsigned cvtpk(float lo, float hi){
  unsigned w;
  asm("v_cvt_pk_bf16_f32 %0, %1, %2" : "=v"(w) : "v"(lo), "v"(hi));
  return w;
}
// cross-half swap: a' = [a.lo32 | b.lo32], b' = [a.hi32 | b.hi32]
__device__ __forceinline__ void plswap(unsigned &a, unsigned &b){
  u32x2 r = __builtin_amdgcn_permlane32_swap(a, b, false, false);
  a = r[0]; b = r[1];
}

#define NHEAD 12
#define HDIM  64
#define HID   768
#define SEQ   512
#define BATCH 32
#define ROWS  (BATCH*SEQ)   // 16384
#define QKVW  2304          // packed qkv row width
#define QCH   128           // q-chunk rows for attention
#define NCHUNK (SEQ/QCH)    // 4
#define FT    128           // flash key tile

// ---------------------------------------------------------------------------
// 256x256 8-phase MFMA GEMM (T2+T3+T4+T5): C[M,N] = A[M,K]*Bt[N,K]^T +bias.
// (unchanged from round 3: counted lgkmcnt chunked MFMA, 1 barrier/phase)
// ---------------------------------------------------------------------------
template<int EPI, typename TR>
__global__ __launch_bounds__(512,2)
void gemm8p(const bf16* __restrict__ A, int lda,
            const bf16* __restrict__ Bt, int ldb,
            bf16* __restrict__ C, int ldc, int K,
            const float* __restrict__ bias,
            const TR* __restrict__ res, int ldres)
{
  __shared__ __align__(16) bf16 tileLds[4][256*64];   // [buf*2 + (0=A,1=B)]

  const int tid  = threadIdx.x;
  const int wave = tid>>6, lane = tid&63;
  const int r = lane&15, qd = lane>>4;
  const int wr = wave>>2, wc = wave&3;        // 2M x 4N waves
  const int m0 = blockIdx.y*256, n0 = blockIdx.x*256;
  const int NTK = K>>6;
  const int wbase = wave*512;                 // per-wave LDS element base

  const int sr = tid>>3, sp = tid&7;
  const bf16* pA = A  + (size_t)(m0+sr)*lda + ((sp^(sr&7))<<3);
  const bf16* pB = Bt + (size_t)(n0+sr)*ldb + ((sp^(sr&7))<<3);

  auto stage = [&](int H){
    const int u = H>>2, idx = H&3, bufi = u&1;
    const size_t kof = (size_t)u*64;
    if (idx==0){            // A half0
      gl_lds16(pA + kof,                    tileLds[bufi*2] + wbase);
      gl_lds16(pA + kof + (size_t)64*lda,   tileLds[bufi*2] + wbase + 4096);
    } else if (idx==3){     // A half1
      gl_lds16(pA + kof + (size_t)128*lda,  tileLds[bufi*2] + 8192 + wbase);
      gl_lds16(pA + kof + (size_t)192*lda,  tileLds[bufi*2] + 8192 + wbase + 4096);
    } else {                // B half (idx1->h0, idx2->h1)
      const int h = idx-1;
      gl_lds16(pB + kof + (size_t)(h*128)*ldb,
               tileLds[bufi*2+1] + h*8192 + wbase);
      gl_lds16(pB + kof + (size_t)(h*128+64)*ldb,
               tileLds[bufi*2+1] + h*8192 + wbase + 4096);
    }
  };

  auto rdA = [&](const bf16* base, int mi, int ks)->bf16x8{
    const int row = mi*32 + wr*16 + r;
    return *(const bf16x8*)(base + row*64 + ((((ks<<2)|qd) ^ (r&7))<<3));
  };
  auto rdB = [&](const bf16* base, int nj, int ks)->bf16x8{
    const int row = nj*64 + wc*16 + r;
    return *(const bf16x8*)(base + row*64 + ((((ks<<2)|qd) ^ (r&7))<<3));
  };

  #pragma unroll
  for (int H=0; H<7; ++H) stage(H);
  asm volatile("s_waitcnt vmcnt(6)" ::: "memory");
  __builtin_amdgcn_s_barrier();

  f32x4 acc[8][4] = {};

  for (int t=0; t<NTK; ++t){
    const bf16* a = tileLds[(t&1)*2];
    const bf16* b = tileLds[(t&1)*2+1];
    const int Hb = 4*t + 6;
    const int Hmax = 4*NTK;
    bf16x8 af[4][2], bn0[2][2], bn1[2][2];

    // ---- phase 1: quadrant (m0,n0); 12 reads; stage (t+1) A1
    af[0][0]=rdA(a,0,0); af[0][1]=rdA(a,0,1);
    af[1][0]=rdA(a,1,0); af[1][1]=rdA(a,1,1);
    bn0[0][0]=rdB(b,0,0); bn0[0][1]=rdB(b,0,1);
    bn0[1][0]=rdB(b,1,0); bn0[1][1]=rdB(b,1,1);
    __builtin_amdgcn_sched_barrier(0);
    af[2][0]=rdA(a,2,0); af[2][1]=rdA(a,2,1);
    af[3][0]=rdA(a,3,0); af[3][1]=rdA(a,3,1);
    if (Hb+1 < Hmax) stage(Hb+1);
    LGKM(4);                               // first 8 reads landed
    __builtin_amdgcn_s_setprio(1);
    #pragma unroll
    for (int mi=0;mi<2;mi++)
      #pragma unroll
      for (int nj=0;nj<2;nj++){
        acc[mi][nj] = MFMA16(af[mi][0], bn0[nj][0], acc[mi][nj],0,0,0);
        acc[mi][nj] = MFMA16(af[mi][1], bn0[nj][1], acc[mi][nj],0,0,0);
      }
    LGKM(0);                               // af[2..3] landed
    #pragma unroll
    for (int mi=2;mi<4;mi++)
      #pragma unroll
      for (int nj=0;nj<2;nj++){
        acc[mi][nj] = MFMA16(af[mi][0], bn0[nj][0], acc[mi][nj],0,0,0);
        acc[mi][nj] = MFMA16(af[mi][1], bn0[nj][1], acc[mi][nj],0,0,0);
      }
    __builtin_amdgcn_s_setprio(0);
    __builtin_amdgcn_s_barrier();

    // ---- phase 2: quadrant (m0,n1); 4 reads; stage (t+2) A0
    bn1[0][0]=rdB(b,2,0); bn1[0][1]=rdB(b,2,1);
    __builtin_amdgcn_sched_barrier(0);
    bn1[1][0]=rdB(b,3,0); bn1[1][1]=rdB(b,3,1);
    if (Hb+2 < Hmax) stage(Hb+2);
    LGKM(2);
    __builtin_amdgcn_s_setprio(1);
    #pragma unroll
    for (int mi=0;mi<4;mi++){
      acc[mi][2] = MFMA16(af[mi][0], bn1[0][0], acc[mi][2],0,0,0);
      acc[mi][2] = MFMA16(af[mi][1], bn1[0][1], acc[mi][2],0,0,0);
    }
    LGKM(0);
    #pragma unroll
    for (int mi=0;mi<4;mi++){
      acc[mi][3] = MFMA16(af[mi][0], bn1[1][0], acc[mi][3],0,0,0);
      acc[mi][3] = MFMA16(af[mi][1], bn1[1][1], acc[mi][3],0,0,0);
    }
    __builtin_amdgcn_s_setprio(0);
    __builtin_amdgcn_s_barrier();

    // ---- phase 3: quadrant (m1,n1); 8 reads (af := m1); stage (t+2) B0
    af[0][0]=rdA(a,4,0); af[0][1]=rdA(a,4,1);
    af[1][0]=rdA(a,5,0); af[1][1]=rdA(a,5,1);
    __builtin_amdgcn_sched_barrier(0);
    af[2][0]=rdA(a,6,0); af[2][1]=rdA(a,6,1);
    af[3][0]=rdA(a,7,0); af[3][1]=rdA(a,7,1);
    if (Hb+3 < Hmax) stage(Hb+3);
    LGKM(4);
    __builtin_amdgcn_s_setprio(1);
    #pragma unroll
    for (int mi=0;mi<2;mi++)
      #pragma unroll
      for (int nj=0;nj<2;nj++){
        acc[4+mi][2+nj] = MFMA16(af[mi][0], bn1[nj][0], acc[4+mi][2+nj],0,0,0);
        acc[4+mi][2+nj] = MFMA16(af[mi][1], bn1[nj][1], acc[4+mi][2+nj],0,0,0);
      }
    LGKM(0);
    #pragma unroll
    for (int mi=2;mi<4;mi++)
      #pragma unroll
      for (int nj=0;nj<2;nj++){
        acc[4+mi][2+nj] = MFMA16(af[mi][0], bn1[nj][0], acc[4+mi][2+nj],0,0,0);
        acc[4+mi][2+nj] = MFMA16(af[mi][1], bn1[nj][1], acc[4+mi][2+nj],0,0,0);
      }
    __builtin_amdgcn_s_setprio(0);
    __builtin_amdgcn_s_barrier();

    // ---- phase 4: quadrant (m1,n0); 0 reads (af=m1, bn0 live); stage (t+2) B1
    if (Hb+4 < Hmax) stage(Hb+4);
    __builtin_amdgcn_s_setprio(1);
    #pragma unroll
    for (int mi=0;mi<4;mi++)
      #pragma unroll
      for (int nj=0;nj<2;nj++){
        acc[4+mi][nj] = MFMA16(af[mi][0], bn0[nj][0], acc[4+mi][nj],0,0,0);
        acc[4+mi][nj] = MFMA16(af[mi][1], bn0[nj][1], acc[4+mi][nj],0,0,0);
      }
    __builtin_amdgcn_s_setprio(0);
    if (t < NTK-2) { asm volatile("s_waitcnt vmcnt(6)" ::: "memory"); }
    else           { asm volatile("s_waitcnt vmcnt(0)" ::: "memory"); }
    __builtin_amdgcn_s_barrier();
  }

  // epilogue
  float bs[4];
  #pragma unroll
  for (int nj=0;nj<4;nj++)
    bs[nj] = bias ? bias[n0 + nj*64 + wc*16 + r] : 0.f;
  #pragma unroll
  for (int mi=0;mi<8;mi++){
    #pragma unroll
    for (int nj=0;nj<4;nj++){
      #pragma unroll
      for (int i=0;i<4;i++){
        const int mm = m0 + mi*32 + wr*16 + qd*4 + i;
        const int nn = n0 + nj*64 + wc*16 + r;
        float v = acc[mi][nj][i] + bs[nj];
        if (EPI==1) v = gelu_f(v);
        if (EPI==2) v += ldf(res, (size_t)mm*ldres + nn);
        C[(size_t)mm*ldc + nn] = f2b(v);
      }
    }
  }
}

// ---------------------------------------------------------------------------
// Fused flash attention v3: swapped-QK^T 32x32 (T12 architecture).
// One block = one (b,h) x 128-row q-chunk; wave owns 32 q-rows.
// - QK^T = mfma32(K,Q) -> S^T[k][q]: lane owns ONE q (col=lane&31); k-values
//   in 4x f32x16 regs (k=(reg&3)+8*(reg>>2)+4*hi per 32-key block).
// - mask folded into MFMA C-init (smask = 8*mask staged in LDS, b128
//   broadcast reads) -> zero VALU.
// - softmax: in-register reduce + ONE shfl_xor(32) (was 64 ds_swizzle/tile).
// - P stays in registers: cvt_pk_bf16 pairs + permlane32_swap assemble PV
//   B-frags (32 packs + 16 swaps/tile); NO P LDS roundtrip.
// - PV = mfma32(V^T, P) -> O^T[d][q]; packed b64 global stores.
// K/V staging + 3-barrier pipeline unchanged. LDS: Ks16K+Vts16K+smask=32.5K.
// ---------------------------------------------------------------------------
__global__ __launch_bounds__(256)
void flash_attn(const bf16* __restrict__ qkv, const bf16* __restrict__ vtb,
                const float* __restrict__ mask, bf16* __restrict__ ctx)
{
  const int qc = blockIdx.x;
  const int z  = blockIdx.y;
  const int b  = z / NHEAD, h = z - b*NHEAD;
  const int q0 = qc*QCH;

  __shared__ __align__(16) bf16 Ks[FT*64];
  __shared__ __align__(16) bf16 Vts[64*FT];
  __shared__ __align__(16) float smask[FT];   // pre-scaled by 8 (acc domain)

  const int tid = threadIdx.x;
  const int wave = tid>>6, lane = tid&63;
  const int l31 = lane&31, hi = lane>>5;
  const int wr = wave;                        // wave owns q-rows wr*32..+32

  const bf16* Qg = qkv + ((size_t)(b*SEQ + q0))*QKVW + h*HDIM;
  const bf16* Kg = qkv + ((size_t)b*SEQ)*QKVW + 768 + h*HDIM;
  const bf16* Vg = vtb + (size_t)z*HDIM*SEQ;

  auto stageK = [&](int k0){
    #pragma unroll
    for (int c0=0;c0<1024;c0+=256){          // K tile 128 rows x 8 chunks
      int c = c0+tid, row = c>>3, pos = c&7;
      gl_lds16(Kg + (size_t)(k0+row)*QKVW + ((pos^(row&7))*8),
               Ks + (size_t)(c0 + wave*64)*8);
    }
  };
  auto stageV = [&](int k0){
    #pragma unroll
    for (int c0=0;c0<1024;c0+=256){          // Vt tile 64 rows x 16 chunks
      int c = c0+tid, row = c>>4, pos = c&15;
      gl_lds16(Vg + (size_t)row*SEQ + k0 + ((pos^(row&7))*8),
               Vts + (size_t)(c0 + wave*64)*8);
    }
  };

  // prologue: stage tile 0 + mask(0); Q -> registers as B-frags:
  // qf[hs]: col q = l31, contraction c = hi*8+j, hd = hs*16 + c
  stageK(0);
  stageV(0);
  if (tid < FT) smask[tid] = 8.0f*mask[(size_t)b*SEQ + tid];
  bf16x8 qf[4];
  #pragma unroll
  for (int hs=0;hs<4;hs++)
    qf[hs] = *(const bf16x8*)(Qg + (size_t)(wr*32+l31)*QKVW + hs*16 + hi*8);

  f32x16 accO[2] = {};               // O^T[d][q]: col q=l31, row d=dt*32+pat
  float mrun = -1e30f, lrun = 0.f;

  for (int k0=0; k0<SEQ; k0+=FT){
    __syncthreads();                 // K,V,smask for tile t ready

    // S^T = K Q^T (+8*mask via C-init): 4 key-blocks of 32
    f32x16 S[4];
    #pragma unroll
    for (int kb=0;kb<4;kb++){
      #pragma unroll
      for (int rq=0;rq<4;rq++){
        f32x4 mq = *(const f32x4*)(smask + kb*32 + rq*8 + hi*4);
        S[kb][rq*4+0]=mq[0]; S[kb][rq*4+1]=mq[1];
        S[kb][rq*4+2]=mq[2]; S[kb][rq*4+3]=mq[3];
      }
    }
    #pragma unroll
    for (int hs=0;hs<4;hs++){
      bf16x8 kf[4];
      #pragma unroll
      for (int kb=0;kb<4;kb++){
        int row = kb*32 + l31;
        int ch  = hs*2 + hi;
        kf[kb] = *(const bf16x8*)(Ks + row*64 + ((ch^(row&7))*8));
      }
      #pragma unroll
      for (int kb=0;kb<4;kb++)
        S[kb] = MFMA32(kf[kb], qf[hs], S[kb], 0,0,0);
    }

    __syncthreads();                 // barrier A: all waves done reading Ks
    if (k0+FT < SEQ) stageK(k0+FT);  // K(t+1) flies under softmax+PV

    // online softmax: lane owns one q-row; in-reg reduce + 1 shfl over halves
    float mx = -1e30f;
    #pragma unroll
    for (int kb=0;kb<4;kb++)
      #pragma unroll
      for (int e=0;e<16;e++){
        float v = S[kb][e]*0.125f;
        S[kb][e] = v;
        mx = fmaxf(mx, v);
      }
    mx = fmaxf(mx, __shfl_xor(mx, 32));
    float mnew = fmaxf(mrun, mx);
    float alpha = __expf(mrun - mnew);
    mrun = mnew;
    float ps = 0.f;
    #pragma unroll
    for (int kb=0;kb<4;kb++)
      #pragma unroll
      for (int e=0;e<16;e++){
        float p = __expf(S[kb][e] - mnew);
        S[kb][e] = p;
        ps += p;
      }
    ps += __shfl_xor(ps, 32);
    lrun = lrun*alpha + ps;
    #pragma unroll
    for (int dt=0;dt<2;dt++)
      #pragma unroll
      for (int e=0;e<16;e++)
        accO[dt][e] *= alpha;

    // PV per key-block: pack P -> bf16 B-frags in-register, mfma with V^T
    #pragma unroll
    for (int kb=0;kb<4;kb++){
      unsigned w[8];
      #pragma unroll
      for (int m=0;m<8;m++)
        w[m] = cvtpk(S[kb][2*m], S[kb][2*m+1]);
      // frag(ks2=0): words from (w0..w3); frag(ks2=1): (w4..w7)
      plswap(w[0], w[2]);  plswap(w[1], w[3]);
      plswap(w[4], w[6]);  plswap(w[5], w[7]);
      union { unsigned u[4]; bf16x8 v; } pf0, pf1;
      pf0.u[0]=w[0]; pf0.u[1]=w[1]; pf0.u[2]=w[2]; pf0.u[3]=w[3];
      pf1.u[0]=w[4]; pf1.u[1]=w[5]; pf1.u[2]=w[6]; pf1.u[3]=w[7];
      #pragma unroll
      for (int ks2=0;ks2<2;ks2++){
        const bf16x8 pf = ks2 ? pf1.v : pf0.v;
        #pragma unroll
        for (int dt=0;dt<2;dt++){
          int row = dt*32 + l31;
          int ch  = kb*4 + ks2*2 + hi;      // s-chunk of 8 within 128
          bf16x8 vf = *(const bf16x8*)(Vts + row*FT + ((ch^(row&7))*8));
          accO[dt] = MFMA32(vf, pf, accO[dt], 0,0,0);
        }
      }
    }

    __syncthreads();                 // barrier B: all waves done reading Vts
    if (k0+FT < SEQ){
      stageV(k0+FT);                 // V(t+1); drained at next loop-top sync
      if (tid < FT) smask[tid] = 8.0f*mask[(size_t)b*SEQ + k0+FT + tid];
    }
  }

  // epilogue: O[q][d] = accO^T / lrun ; packed 4x bf16 (8B) stores
  float invl = 1.0f/lrun;
  bf16* Cg = ctx + ((size_t)(b*SEQ + q0 + wr*32 + l31))*HID + h*HDIM;
  #pragma unroll
  for (int dt=0;dt<2;dt++){
    #pragma unroll
    for (int rq=0;rq<4;rq++){
      union { unsigned long long u; __bf16 hh[4]; } pk;
      #pragma unroll
      for (int i=0;i<4;i++)
        pk.hh[i] = (__bf16)(accO[dt][rq*4+i]*invl);
      *(unsigned long long*)(Cg + dt*32 + rq*8 + hi*4) = pk.u;
    }
  }
}

// ---------------------------------------------------------------------------
// Weight transpose + fp32->bf16 cast (unchanged)
// ---------------------------------------------------------------------------
__global__ void transpose_cast(const float* __restrict__ in, bf16* __restrict__ out,
                               int R, int C)
{
  __shared__ float tile[32][33];
  int bc = blockIdx.x*32, br = blockIdx.y*32;
  int tx = threadIdx.x, ty = threadIdx.y;
  #pragma unroll
  for (int i=ty;i<32;i+=8)
    tile[i][tx] = in[(size_t)(br+i)*C + bc+tx];
  __syncthreads();
  #pragma unroll
  for (int i=ty;i<32;i+=8)
    out[(size_t)(bc+i)*R + br+tx] = f2b(tile[tx][i]);
}

__global__ void transpose_cast4(const float* __restrict__ w0, const float* __restrict__ w1,
                                const float* __restrict__ w2, const float* __restrict__ w3,
                                bf16* __restrict__ out)
{
  const float* in = blockIdx.z==0?w0 : blockIdx.z==1?w1 : blockIdx.z==2?w2 : w3;
  bf16* o = out + (size_t)blockIdx.z*768*768;
  __shared__ float tile[32][33];
  int bc = blockIdx.x*32, br = blockIdx.y*32;
  int tx = threadIdx.x, ty = threadIdx.y;
  #pragma unroll
  for (int i=ty;i<32;i+=8)
    tile[i][tx] = in[(size_t)(br+i)*768 + bc+tx];
  __syncthreads();
  #pragma unroll
  for (int i=ty;i<32;i+=8)
    o[(size_t)(bc+i)*768 + br+tx] = f2b(tile[tx][i]);
}

__global__ __launch_bounds__(256)
void castX(const float* __restrict__ in, bf16* __restrict__ out)
{
  int i = blockIdx.x*256 + threadIdx.x;
  float4 f = ((const float4*)in)[i];
  union{ unsigned long long u; __bf16 h[4]; } pk;
  pk.h[0]=(__bf16)f.x; pk.h[1]=(__bf16)f.y; pk.h[2]=(__bf16)f.z; pk.h[3]=(__bf16)f.w;
  ((unsigned long long*)out)[i] = pk.u;
}

__global__ void concat_bias(const float* __restrict__ a, const float* __restrict__ b,
                            const float* __restrict__ c, float* __restrict__ o)
{
  int i = blockIdx.x*256 + threadIdx.x;
  if (i < 768) o[i] = a[i];
  else if (i < 1536) o[i] = b[i-768];
  else if (i < 2304) o[i] = c[i-1536];
}

// V part of qkv [row][2304] -> Vt [z=(b,h)][d][s]
__global__ void vtrans(const bf16* __restrict__ v, bf16* __restrict__ vt)
{
  int z = blockIdx.z; int b = z/NHEAD, h = z - b*NHEAD;
  int d0 = blockIdx.x*32, s0 = blockIdx.y*32;
  __shared__ bf16 t[32][33];
  int tx = threadIdx.x, ty = threadIdx.y;
  #pragma unroll
  for (int i=ty;i<32;i+=8)
    t[i][tx] = v[(size_t)(b*SEQ + s0+i)*QKVW + h*HDIM + d0+tx];
  __syncthreads();
  #pragma unroll
  for (int i=ty;i<32;i+=8)
    vt[(size_t)z*HDIM*SEQ + (size_t)(d0+i)*SEQ + s0+tx] = t[tx][i];
}

// ---------------------------------------------------------------------------
// LayerNorm over 768 cols: ONE WAVE per row. bf16x4/float4 vectorized
// loads+stores, pure-shfl reduce, no LDS, no syncthreads. 4 rows/block.
// ---------------------------------------------------------------------------
template<typename TO>
__global__ __launch_bounds__(256)
void ln768(const bf16* __restrict__ y, const float* __restrict__ g,
           const float* __restrict__ be, TO* __restrict__ dst)
{
  const int wave = threadIdx.x>>6, lane = threadIdx.x&63;
  const size_t row = (size_t)blockIdx.x*4 + wave;
  const bf16* yr = y + row*HID;
  float x[12];
  float s = 0.f, q = 0.f;
  #pragma unroll
  for (int c=0;c<3;c++){
    bf16x4 v = *(const bf16x4*)(yr + c*256 + lane*4);
    #pragma unroll
    for (int j=0;j<4;j++){
      float f = (float)v[j];
      x[c*4+j] = f;
      s += f; q += f*f;
    }
  }
  #pragma unroll
  for (int off=1; off<64; off<<=1){ s += __shfl_xor(s, off); q += __shfl_xor(q, off); }
  float mean = s*(1.0f/HID);
  float var  = q*(1.0f/HID) - mean*mean;
  float inv  = rsqrtf(var + 1e-12f);
  TO* dr = dst + row*HID;
  #pragma unroll
  for (int c=0;c<3;c++){
    float4 gg = *(const float4*)(g  + c*256 + lane*4);
    float4 bb = *(const float4*)(be + c*256 + lane*4);
    st4(dr + c*256 + lane*4,
        (x[c*4+0]-mean)*inv*gg.x + bb.x,
        (x[c*4+1]-mean)*inv*gg.y + bb.y,
        (x[c*4+2]-mean)*inv*gg.z + bb.z,
        (x[c*4+3]-mean)*inv*gg.w + bb.w);
  }
}

// ---------------------------------------------------------------------------
// Dialog (CLS) block: 32 rows total (unchanged)
// ---------------------------------------------------------------------------
__global__ __launch_bounds__(256)
void cls_proj(const bf16* __restrict__ x2,
              const float* __restrict__ Wq, const float* __restrict__ bq,
              const float* __restrict__ Wk, const float* __restrict__ bk,
              const float* __restrict__ Wv, const float* __restrict__ bv,
              bf16* __restrict__ oq, bf16* __restrict__ ok, bf16* __restrict__ ov)
{
  int mat = blockIdx.x, row = blockIdx.y;
  const float* W  = mat==0 ? Wq : (mat==1 ? Wk : Wv);
  const float* bi = mat==0 ? bq : (mat==1 ? bk : bv);
  bf16* out       = mat==0 ? oq : (mat==1 ? ok : ov);
  __shared__ float a[HID];
  const bf16* xr = x2 + (size_t)row*SEQ*HID;
  for (int i=threadIdx.x;i<HID;i+=256) a[i] = b2f(xr[i]);
  __syncthreads();
  for (int c0=0;c0<HID;c0+=256){
    int col = c0 + threadIdx.x;
    float acc = 0.f;
    for (int k=0;k<HID;k++) acc += a[k]*W[(size_t)k*HID + col];
    out[(size_t)row*HID + col] = f2b(acc + bi[col]);
  }
}

__global__ __launch_bounds__(64)
void cls_attn(const bf16* __restrict__ q, const bf16* __restrict__ k,
              const bf16* __restrict__ v, bf16* __restrict__ ctx)
{
  int z = blockIdx.x; int bb = z/NHEAD, h = z - bb*NHEAD;
  __shared__ float P[8][8];
  int t = threadIdx.x;
  int qi = t>>3, ki = t&7;
  float s = 0.f;
  for (int d=0; d<HDIM; d++)
    s += b2f(q[(size_t)(bb*8+qi)*HID + h*HDIM + d]) *
         b2f(k[(size_t)(bb*8+ki)*HID + h*HDIM + d]);
  s = s*0.125f + (ki >= qi ? -10000.0f : 0.0f);
  float m = s;
  #pragma unroll
  for (int off=4; off; off>>=1) m = fmaxf(m, __shfl_xor(m, off, 8));
  float e = __expf(s - m);
  float sum = e;
  #pragma unroll
  for (int off=4; off; off>>=1) sum += __shfl_xor(sum, off, 8);
  P[qi][ki] = e/sum;
  __syncthreads();
  for (int q2=0; q2<8; q2++){
    float acc = 0.f;
    #pragma unroll
    for (int k2=0; k2<8; k2++)
      acc += P[q2][k2] * b2f(v[(size_t)(bb*8+k2)*HID + h*HDIM + t]);
    ctx[(size_t)(bb*8+q2)*HID + h*HDIM + t] = f2b(acc);
  }
}

__global__ __launch_bounds__(256)
void cls_out(const bf16* __restrict__ ctx, const float* __restrict__ Wo,
             const float* __restrict__ bo, const float* __restrict__ g,
             const float* __restrict__ be, bf16* __restrict__ x2)
{
  int row = blockIdx.x;
  __shared__ float a[HID];
  __shared__ float yrow[HID];
  const bf16* cr = ctx + (size_t)row*HID;
  bf16* xr = x2 + (size_t)row*SEQ*HID;
  for (int i=threadIdx.x;i<HID;i+=256) a[i] = b2f(cr[i]);
  __syncthreads();
  for (int c0=0;c0<HID;c0+=256){
    int col = c0 + threadIdx.x;
    float acc = 0.f;
    for (int k=0;k<HID;k++) acc += a[k]*Wo[(size_t)k*HID + col];
    yrow[col] = acc + bo[col] + b2f(xr[col]);
  }
  __syncthreads();
  int t = threadIdx.x;
  float x0 = yrow[t], x1 = yrow[t+256], x2v = yrow[t+512];
  float s = x0+x1+x2v, qq = x0*x0+x1*x1+x2v*x2v;
  #pragma unroll
  for (int off=32; off; off>>=1){ s += __shfl_xor(s, off); qq += __shfl_xor(qq, off); }
  __shared__ float rs[4], rq[4];
  int wv = t>>6;
  if ((t&63)==0){ rs[wv]=s; rq[wv]=qq; }
  __syncthreads();
  s = rs[0]+rs[1]+rs[2]+rs[3];
  qq = rq[0]+rq[1]+rq[2]+rq[3];
  float mean = s*(1.0f/HID);
  float var  = qq*(1.0f/HID) - mean*mean;
  float inv  = rsqrtf(var + 1e-12f);
  xr[t    ] = f2b((x0 -mean)*inv*g[t    ] + be[t    ]);
  xr[t+256] = f2b((x1 -mean)*inv*g[t+256] + be[t+256]);
  xr[t+512] = f2b((x2v-mean)*inv*g[t+512] + be[t+512]);
}

// ---------------------------------------------------------------------------
extern "C" void kernel_launch(void* const* d_in, const int* in_sizes, int n_in,
                              void* d_out, int out_size, void* d_ws, size_t ws_size,
                              hipStream_t stream)
{
  const float* X    = (const float*)d_in[0];
  const float* AM   = (const float*)d_in[1];
  const float* Wq   = (const float*)d_in[2];  const float* bq  = (const float*)d_in[3];
  const float* Wk   = (const float*)d_in[4];  const float* bk  = (const float*)d_in[5];
  const float* Wv   = (const float*)d_in[6];  const float* bv  = (const float*)d_in[7];
  const float* Wao  = (const float*)d_in[8];  const float* bao = (const float*)d_in[9];
  const float* ln1g = (const float*)d_in[10]; const float* ln1b= (const float*)d_in[11];
  const float* dWq  = (const float*)d_in[12]; const float* dbq = (const float*)d_in[13];
  const float* dWk  = (const float*)d_in[14]; const float* dbk = (const float*)d_in[15];
  const float* dWv  = (const float*)d_in[16]; const float* dbv = (const float*)d_in[17];
  const float* dWo  = (const float*)d_in[18]; const float* dbo = (const float*)d_in[19];
  const float* dlng = (const float*)d_in[20]; const float* dlnb= (const float*)d_in[21];
  const float* Wi   = (const float*)d_in[22]; const float* bi  = (const float*)d_in[23];
  const float* Wo2  = (const float*)d_in[24]; const float* bo2 = (const float*)d_in[25];
  const float* ln2g = (const float*)d_in[26]; const float* ln2b= (const float*)d_in[27];
  float* OUT = (float*)d_out;

  char* wp = (char*)d_ws;
  auto alloc = [&](size_t elems)->bf16*{
    bf16* p = (bf16*)wp;
    wp += ((elems*sizeof(bf16) + 255)/256)*256;
    return p;
  };
  bf16* wtq  = alloc(768*768);       // wtq..wtv contiguous => fused QKV B
  bf16* wtk  = alloc(768*768);
  bf16* wtv  = alloc(768*768);
  bf16* wtao = alloc(768*768);
  bf16* wti  = alloc((size_t)768*3072);
  bf16* wto2 = alloc((size_t)3072*768);
  float* bqkv = (float*)alloc(2304*2);
  bf16* qkv  = alloc((size_t)ROWS*QKVW);          // } qkv+vtb contiguous:
  bf16* vtb  = alloc((size_t)ROWS*HID);           // } inter aliases both
  bf16* inter = qkv;
  bf16* scb  = alloc((size_t)ROWS*HID);            // y/x2 slab
  bf16* yb   = scb;
  bf16* x2   = scb;
  bf16* ctxb = alloc((size_t)ROWS*HID);
  bf16* xb   = ctxb;   // bf16 X, dead before flash writes ctxb
  bf16* clsq = alloc(32*HID);
  bf16* clsk = alloc(32*HID);
  bf16* clsv = alloc(32*HID);
  bf16* clsc = alloc(32*HID);
  (void)wtk; (void)wtv;

  dim3 T32(32,8);
  transpose_cast4<<<dim3(24,24,4), T32, 0, stream>>>(Wq, Wk, Wv, Wao, wtq);
  transpose_cast<<<dim3(96,24), T32, 0, stream>>>(Wi,  wti, 768, 3072);
  transpose_cast<<<dim3(24,96), T32, 0, stream>>>(Wo2, wto2,3072, 768);
  concat_bias<<<9,256,0,stream>>>(bq, bk, bv, bqkv);
  castX<<<ROWS*HID/4/256,256,0,stream>>>(X, xb);

  // fused QKV projection: [16384,768] @ [768,2304]^T -> qkv[row][2304]
  gemm8p<0,float><<<dim3(9,64),512,0,stream>>>(
      xb,768,  wtq,768,  qkv,QKVW, 768, bqkv, (const float*)nullptr, 0);

  vtrans<<<dim3(2,16,BATCH*NHEAD), T32, 0, stream>>>(qkv + 1536, vtb);

  // fused flash attention -> ctxb
  flash_attn<<<dim3(NCHUNK, BATCH*NHEAD),256,0,stream>>>(qkv, vtb, AM, ctxb);

  // attn out-proj + bias + residual(X fp32) -> yb ; LN1 in place -> x2
  gemm8p<2,float><<<dim3(3,64),512,0,stream>>>(
      ctxb,768,  wtao,768,  yb,768, 768, bao, X, 768);
  ln768<bf16><<<ROWS/4,256,0,stream>>>(yb, ln1g, ln1b, x2);

  // dialog (CLS) block on 32 rows
  cls_proj<<<dim3(3,32),256,0,stream>>>(x2, dWq,dbq, dWk,dbk, dWv,dbv,
                                        clsq, clsk, clsv);
  cls_attn<<<48,64,0,stream>>>(clsq, clsk, clsv, clsc);
  cls_out<<<32,256,0,stream>>>(clsc, dWo, dbo, dlng, dlnb, x2);

  // FFN1: inter = gelu(x2 @ Wi + bi)
  gemm8p<1,float><<<dim3(12,64),512,0,stream>>>(
      x2,768,  wti,768,  inter,3072, 768, bi, (const float*)nullptr, 0);
  // FFN2: y = inter @ Wo2 + bo2 + x2
  gemm8p<2,bf16><<<dim3(3,64),512,0,stream>>>(
      inter,3072,  wto2,3072,  yb,768, 3072, bo2, x2, 768);
  ln768<float><<<ROWS/4,256,0,stream>>>(yb, ln2g, ln2b, OUT);
}

// Round 8
// 780.157 us; speedup vs baseline: 1.0627x; 1.0422x over previous
//
#include <hip/hip_runtime.h>
#include <hip/hip_bf16.h>
#include <math.h>

using bf16 = __hip_bfloat16;
typedef __attribute__((ext_vector_type(8))) __bf16 bf16x8;
typedef __attribute__((ext_vector_type(4))) __bf16 bf16x4;
typedef __attribute__((ext_vector_type(4))) float f32x4;
typedef __attribute__((ext_vector_type(16))) float f32x16;
typedef unsigned int u32x2 __attribute__((ext_vector_type(2)));

__device__ __forceinline__ float b2f(bf16 x){ return __bfloat162float(x); }
__device__ __forceinline__ bf16  f2b(float x){ return __float2bfloat16(x); }
__device__ __forceinline__ float ldf(const float* p, size_t i){ return p[i]; }
__device__ __forceinline__ float ldf(const bf16*  p, size_t i){ return b2f(p[i]); }
__device__ __forceinline__ void stf(float* p, size_t i, float v){ p[i] = v; }
__device__ __forceinline__ void stf(bf16*  p, size_t i, float v){ p[i] = f2b(v); }

// vectorized 4-wide store (fp32 / bf16)
__device__ __forceinline__ void st4(float* p, float a, float b, float c, float d){
  float4 f; f.x=a; f.y=b; f.z=c; f.w=d; *(float4*)p = f;
}
__device__ __forceinline__ void st4(bf16* p, float a, float b, float c, float d){
  bf16x4 o; o[0]=(__bf16)a; o[1]=(__bf16)b; o[2]=(__bf16)c; o[3]=(__bf16)d;
  *(bf16x4*)p = o;
}

// fast gelu: tanh form, |err| ~1e-3
__device__ __forceinline__ float gelu_f(float v){
  float u = v*(0.7978845608f + 0.0356774081f*v*v);
  float e = __expf(2.f*u);
  float t = 1.f - 2.f/(e+1.f);          // tanh(u); saturates correctly at +-inf
  return 0.5f*v*(1.f+t);
}

// async 16B global->LDS (LDS base must be wave-uniform; HW adds lane*16)
typedef const __attribute__((address_space(1))) unsigned int* gas_u32p;
typedef __attribute__((address_space(3))) unsigned int* las_u32p;
__device__ __forceinline__ void gl_lds16(const bf16* g, bf16* l){
  __builtin_amdgcn_global_load_lds((gas_u32p)(const void*)g, (las_u32p)(void*)l, 16, 0, 0);
}

#define MFMA16 __builtin_amdgcn_mfma_f32_16x16x32_bf16
#define MFMA32 __builtin_amdgcn_mfma_f32_32x32x16_bf16

// counted LDS wait + scheduler fence (rule #18: fence required after lgkmcnt)
#define LGKM(N) do { \
  asm volatile("s_waitcnt lgkmcnt(" #N ")" ::: "memory"); \
  __builtin_amdgcn_sched_barrier(0); \
} while(0)

// pack 2 f32 -> 1 u32 of 2 bf16 (T12 recipe; no builtin on gfx950)
__device__ __forceinline__ unsigned cvtpk(float lo, float hi){
  unsigned w;
  asm("v_cvt_pk_bf16_f32 %0, %1, %2" : "=v"(w) : "v"(lo), "v"(hi));
  return w;
}
// cross-half swap: a' = [a.lo32 | b.lo32], b' = [a.hi32 | b.hi32]
__device__ __forceinline__ void plswap(unsigned &a, unsigned &b){
  u32x2 r = __builtin_amdgcn_permlane32_swap(a, b, false, false);
  a = r[0]; b = r[1];
}

#define NHEAD 12
#define HDIM  64
#define HID   768
#define SEQ   512
#define BATCH 32
#define ROWS  (BATCH*SEQ)   // 16384
#define QKVW  2304          // packed qkv row width
#define QCH   128           // q-chunk rows for attention
#define NCHUNK (SEQ/QCH)    // 4
#define FT    128           // flash key tile

// ---------------------------------------------------------------------------
// 256x256 MFMA GEMM v3: cross-phase software pipeline, ONE barrier per K-tile.
// Round-6 diagnosis: 7850 cyc/tile vs LDS-pipe floor 2816 + MFMA 2483 --
// phase-lockstep burst-read/burst-MFMA alternation (4 barriers/tile) kept the
// LDS and matrix pipes from overlapping. v3: reads issued one phase ahead
// with counted lgkm; stage(t+1, other buf) at iter top (readers drained by
// t-1's single barrier); vmcnt(0)+barrier publishes buf; A0(t+1) issues into
// dead afA regs and drains under ph4's MFMA.
//   issue B0,B1 | stage t+1 | LGKM(4)  ph1(A0xB0)
//   issue A1            | LGKM(8)  ph2(A0xB1)
//                       | LGKM(0)  ph3(A1xB1)
//   vmcnt(0) barrier | issue A0(t+1) | ph4(A1xB0)
// EPI: 0=bias, 1=bias+gelu, 2=bias+residual.
// ---------------------------------------------------------------------------
template<int EPI, typename TR>
__global__ __launch_bounds__(512,2)
void gemm8p(const bf16* __restrict__ A, int lda,
            const bf16* __restrict__ Bt, int ldb,
            bf16* __restrict__ C, int ldc, int K,
            const float* __restrict__ bias,
            const TR* __restrict__ res, int ldres)
{
  __shared__ __align__(16) bf16 tileLds[4][256*64];   // [buf*2 + (0=A,1=B)]

  const int tid  = threadIdx.x;
  const int wave = tid>>6, lane = tid&63;
  const int r = lane&15, qd = lane>>4;
  const int wr = wave>>2, wc = wave&3;        // 2M x 4N waves
  const int m0 = blockIdx.y*256, n0 = blockIdx.x*256;
  const int NTK = K>>6;
  const int wbase = wave*512;                 // per-wave LDS element base

  const int sr = tid>>3, sp = tid&7;
  const bf16* pA = A  + (size_t)(m0+sr)*lda + ((sp^(sr&7))<<3);
  const bf16* pB = Bt + (size_t)(n0+sr)*ldb + ((sp^(sr&7))<<3);

  auto stageAll = [&](int t){                 // all 4 half-tiles of tile t
    const int bufi = t&1;
    const size_t kof = (size_t)t*64;
    bf16* la = tileLds[bufi*2]   + wbase;
    bf16* lb = tileLds[bufi*2+1] + wbase;
    gl_lds16(pA + kof,                   la);
    gl_lds16(pA + kof + (size_t)64*lda,  la + 4096);
    gl_lds16(pA + kof + (size_t)128*lda, la + 8192);
    gl_lds16(pA + kof + (size_t)192*lda, la + 12288);
    gl_lds16(pB + kof,                   lb);
    gl_lds16(pB + kof + (size_t)64*ldb,  lb + 4096);
    gl_lds16(pB + kof + (size_t)128*ldb, lb + 8192);
    gl_lds16(pB + kof + (size_t)192*ldb, lb + 12288);
  };

  auto rdA = [&](const bf16* base, int mi, int ks)->bf16x8{
    const int row = mi*32 + wr*16 + r;
    return *(const bf16x8*)(base + row*64 + ((((ks<<2)|qd) ^ (r&7))<<3));
  };
  auto rdB = [&](const bf16* base, int nj, int ks)->bf16x8{
    const int row = nj*64 + wc*16 + r;
    return *(const bf16x8*)(base + row*64 + ((((ks<<2)|qd) ^ (r&7))<<3));
  };

  // prologue: stage tiles 0 and 1; wait tile0; preload A0(0)
  stageAll(0);
  if (NTK > 1) stageAll(1);
  asm volatile("s_waitcnt vmcnt(8)" ::: "memory");
  __builtin_amdgcn_s_barrier();

  f32x4 acc[8][4] = {};
  bf16x8 afA[4][2], afB[4][2], bn0[2][2], bn1[2][2];

  {
    const bf16* a0 = tileLds[0];
    #pragma unroll
    for (int mi=0;mi<4;mi++){ afA[mi][0]=rdA(a0,mi,0); afA[mi][1]=rdA(a0,mi,1); }
    __builtin_amdgcn_sched_barrier(0);
  }

  for (int t=0; t<NTK; ++t){
    const bf16* a = tileLds[(t&1)*2];
    const bf16* b = tileLds[(t&1)*2+1];

    // issue B0, B1 of tile t (order pinned: B0 older than B1)
    bn0[0][0]=rdB(b,0,0); bn0[0][1]=rdB(b,0,1);
    bn0[1][0]=rdB(b,1,0); bn0[1][1]=rdB(b,1,1);
    __builtin_amdgcn_sched_barrier(0);
    bn1[0][0]=rdB(b,2,0); bn1[0][1]=rdB(b,2,1);
    bn1[1][0]=rdB(b,3,0); bn1[1][1]=rdB(b,3,1);
    if (t+2 <= NTK-1+1 && t+1 < NTK) stageAll(t+1);   // stage next tile (other buf)

    LGKM(4);                               // A0(8)+B0(4) done; B1 in flight
    __builtin_amdgcn_s_setprio(1);
    #pragma unroll
    for (int mi=0;mi<4;mi++)
      #pragma unroll
      for (int nj=0;nj<2;nj++){
        acc[mi][nj] = MFMA16(afA[mi][0], bn0[nj][0], acc[mi][nj],0,0,0);
        acc[mi][nj] = MFMA16(afA[mi][1], bn0[nj][1], acc[mi][nj],0,0,0);
      }
    __builtin_amdgcn_s_setprio(0);

    // issue A1 of tile t (afB)
    #pragma unroll
    for (int mi=0;mi<4;mi++){ afB[mi][0]=rdA(a,4+mi,0); afB[mi][1]=rdA(a,4+mi,1); }
    LGKM(8);                               // B1 done; A1 in flight
    __builtin_amdgcn_s_setprio(1);
    #pragma unroll
    for (int mi=0;mi<4;mi++)
      #pragma unroll
      for (int nj=0;nj<2;nj++){
        acc[mi][2+nj] = MFMA16(afA[mi][0], bn1[nj][0], acc[mi][2+nj],0,0,0);
        acc[mi][2+nj] = MFMA16(afA[mi][1], bn1[nj][1], acc[mi][2+nj],0,0,0);
      }
    __builtin_amdgcn_s_setprio(0);

    LGKM(0);                               // A1 done
    __builtin_amdgcn_s_setprio(1);
    #pragma unroll
    for (int mi=0;mi<4;mi++)
      #pragma unroll
      for (int nj=0;nj<2;nj++){
        acc[4+mi][2+nj] = MFMA16(afB[mi][0], bn1[nj][0], acc[4+mi][2+nj],0,0,0);
        acc[4+mi][2+nj] = MFMA16(afB[mi][1], bn1[nj][1], acc[4+mi][2+nj],0,0,0);
      }
    __builtin_amdgcn_s_setprio(0);

    asm volatile("s_waitcnt vmcnt(0)" ::: "memory");   // t+1 staged data landed
    __builtin_amdgcn_s_barrier();                      // publish buf[other]

    if (t+1 < NTK){                        // issue A0(t+1) into dead afA regs
      const bf16* an = tileLds[((t+1)&1)*2];
      #pragma unroll
      for (int mi=0;mi<4;mi++){ afA[mi][0]=rdA(an,mi,0); afA[mi][1]=rdA(an,mi,1); }
      __builtin_amdgcn_sched_barrier(0);
    }

    __builtin_amdgcn_s_setprio(1);         // ph4 overlaps A0(t+1) drain
    #pragma unroll
    for (int mi=0;mi<4;mi++)
      #pragma unroll
      for (int nj=0;nj<2;nj++){
        acc[4+mi][nj] = MFMA16(afB[mi][0], bn0[nj][0], acc[4+mi][nj],0,0,0);
        acc[4+mi][nj] = MFMA16(afB[mi][1], bn0[nj][1], acc[4+mi][nj],0,0,0);
      }
    __builtin_amdgcn_s_setprio(0);
  }

  // epilogue
  float bs[4];
  #pragma unroll
  for (int nj=0;nj<4;nj++)
    bs[nj] = bias ? bias[n0 + nj*64 + wc*16 + r] : 0.f;
  #pragma unroll
  for (int mi=0;mi<8;mi++){
    #pragma unroll
    for (int nj=0;nj<4;nj++){
      #pragma unroll
      for (int i=0;i<4;i++){
        const int mm = m0 + mi*32 + wr*16 + qd*4 + i;
        const int nn = n0 + nj*64 + wc*16 + r;
        float v = acc[mi][nj][i] + bs[nj];
        if (EPI==1) v = gelu_f(v);
        if (EPI==2) v += ldf(res, (size_t)mm*ldres + nn);
        C[(size_t)mm*ldc + nn] = f2b(v);
      }
    }
  }
}

// ---------------------------------------------------------------------------
// Fused flash attention v3: swapped-QK^T 32x32 (unchanged from round 6).
// ---------------------------------------------------------------------------
__global__ __launch_bounds__(256)
void flash_attn(const bf16* __restrict__ qkv, const bf16* __restrict__ vtb,
                const float* __restrict__ mask, bf16* __restrict__ ctx)
{
  const int qc = blockIdx.x;
  const int z  = blockIdx.y;
  const int b  = z / NHEAD, h = z - b*NHEAD;
  const int q0 = qc*QCH;

  __shared__ __align__(16) bf16 Ks[FT*64];
  __shared__ __align__(16) bf16 Vts[64*FT];
  __shared__ __align__(16) float smask[FT];   // pre-scaled by 8 (acc domain)

  const int tid = threadIdx.x;
  const int wave = tid>>6, lane = tid&63;
  const int l31 = lane&31, hi = lane>>5;
  const int wr = wave;                        // wave owns q-rows wr*32..+32

  const bf16* Qg = qkv + ((size_t)(b*SEQ + q0))*QKVW + h*HDIM;
  const bf16* Kg = qkv + ((size_t)b*SEQ)*QKVW + 768 + h*HDIM;
  const bf16* Vg = vtb + (size_t)z*HDIM*SEQ;

  auto stageK = [&](int k0){
    #pragma unroll
    for (int c0=0;c0<1024;c0+=256){          // K tile 128 rows x 8 chunks
      int c = c0+tid, row = c>>3, pos = c&7;
      gl_lds16(Kg + (size_t)(k0+row)*QKVW + ((pos^(row&7))*8),
               Ks + (size_t)(c0 + wave*64)*8);
    }
  };
  auto stageV = [&](int k0){
    #pragma unroll
    for (int c0=0;c0<1024;c0+=256){          // Vt tile 64 rows x 16 chunks
      int c = c0+tid, row = c>>4, pos = c&15;
      gl_lds16(Vg + (size_t)row*SEQ + k0 + ((pos^(row&7))*8),
               Vts + (size_t)(c0 + wave*64)*8);
    }
  };

  stageK(0);
  stageV(0);
  if (tid < FT) smask[tid] = 8.0f*mask[(size_t)b*SEQ + tid];
  bf16x8 qf[4];
  #pragma unroll
  for (int hs=0;hs<4;hs++)
    qf[hs] = *(const bf16x8*)(Qg + (size_t)(wr*32+l31)*QKVW + hs*16 + hi*8);

  f32x16 accO[2] = {};               // O^T[d][q]: col q=l31, row d=dt*32+pat
  float mrun = -1e30f, lrun = 0.f;

  for (int k0=0; k0<SEQ; k0+=FT){
    __syncthreads();                 // K,V,smask for tile t ready

    // S^T = K Q^T (+8*mask via C-init): 4 key-blocks of 32
    f32x16 S[4];
    #pragma unroll
    for (int kb=0;kb<4;kb++){
      #pragma unroll
      for (int rq=0;rq<4;rq++){
        f32x4 mq = *(const f32x4*)(smask + kb*32 + rq*8 + hi*4);
        S[kb][rq*4+0]=mq[0]; S[kb][rq*4+1]=mq[1];
        S[kb][rq*4+2]=mq[2]; S[kb][rq*4+3]=mq[3];
      }
    }
    #pragma unroll
    for (int hs=0;hs<4;hs++){
      bf16x8 kf[4];
      #pragma unroll
      for (int kb=0;kb<4;kb++){
        int row = kb*32 + l31;
        int ch  = hs*2 + hi;
        kf[kb] = *(const bf16x8*)(Ks + row*64 + ((ch^(row&7))*8));
      }
      #pragma unroll
      for (int kb=0;kb<4;kb++)
        S[kb] = MFMA32(kf[kb], qf[hs], S[kb], 0,0,0);
    }

    __syncthreads();                 // barrier A: all waves done reading Ks
    if (k0+FT < SEQ) stageK(k0+FT);  // K(t+1) flies under softmax+PV

    // online softmax: lane owns one q-row; in-reg reduce + 1 shfl over halves
    float mx = -1e30f;
    #pragma unroll
    for (int kb=0;kb<4;kb++)
      #pragma unroll
      for (int e=0;e<16;e++){
        float v = S[kb][e]*0.125f;
        S[kb][e] = v;
        mx = fmaxf(mx, v);
      }
    mx = fmaxf(mx, __shfl_xor(mx, 32));
    float mnew = fmaxf(mrun, mx);
    float alpha = __expf(mrun - mnew);
    mrun = mnew;
    float ps = 0.f;
    #pragma unroll
    for (int kb=0;kb<4;kb++)
      #pragma unroll
      for (int e=0;e<16;e++){
        float p = __expf(S[kb][e] - mnew);
        S[kb][e] = p;
        ps += p;
      }
    ps += __shfl_xor(ps, 32);
    lrun = lrun*alpha + ps;
    #pragma unroll
    for (int dt=0;dt<2;dt++)
      #pragma unroll
      for (int e=0;e<16;e++)
        accO[dt][e] *= alpha;

    // PV per key-block: pack P -> bf16 B-frags in-register, mfma with V^T
    #pragma unroll
    for (int kb=0;kb<4;kb++){
      unsigned w[8];
      #pragma unroll
      for (int m=0;m<8;m++)
        w[m] = cvtpk(S[kb][2*m], S[kb][2*m+1]);
      plswap(w[0], w[2]);  plswap(w[1], w[3]);
      plswap(w[4], w[6]);  plswap(w[5], w[7]);
      union { unsigned u[4]; bf16x8 v; } pf0, pf1;
      pf0.u[0]=w[0]; pf0.u[1]=w[1]; pf0.u[2]=w[2]; pf0.u[3]=w[3];
      pf1.u[0]=w[4]; pf1.u[1]=w[5]; pf1.u[2]=w[6]; pf1.u[3]=w[7];
      #pragma unroll
      for (int ks2=0;ks2<2;ks2++){
        const bf16x8 pf = ks2 ? pf1.v : pf0.v;
        #pragma unroll
        for (int dt=0;dt<2;dt++){
          int row = dt*32 + l31;
          int ch  = kb*4 + ks2*2 + hi;      // s-chunk of 8 within 128
          bf16x8 vf = *(const bf16x8*)(Vts + row*FT + ((ch^(row&7))*8));
          accO[dt] = MFMA32(vf, pf, accO[dt], 0,0,0);
        }
      }
    }

    __syncthreads();                 // barrier B: all waves done reading Vts
    if (k0+FT < SEQ){
      stageV(k0+FT);                 // V(t+1); drained at next loop-top sync
      if (tid < FT) smask[tid] = 8.0f*mask[(size_t)b*SEQ + k0+FT + tid];
    }
  }

  // epilogue: O[q][d] = accO^T / lrun ; packed 4x bf16 (8B) stores
  float invl = 1.0f/lrun;
  bf16* Cg = ctx + ((size_t)(b*SEQ + q0 + wr*32 + l31))*HID + h*HDIM;
  #pragma unroll
  for (int dt=0;dt<2;dt++){
    #pragma unroll
    for (int rq=0;rq<4;rq++){
      union { unsigned long long u; __bf16 hh[4]; } pk;
      #pragma unroll
      for (int i=0;i<4;i++)
        pk.hh[i] = (__bf16)(accO[dt][rq*4+i]*invl);
      *(unsigned long long*)(Cg + dt*32 + rq*8 + hi*4) = pk.u;
    }
  }
}

// ---------------------------------------------------------------------------
// Weight transpose + fp32->bf16 cast (unchanged)
// ---------------------------------------------------------------------------
__global__ void transpose_cast(const float* __restrict__ in, bf16* __restrict__ out,
                               int R, int C)
{
  __shared__ float tile[32][33];
  int bc = blockIdx.x*32, br = blockIdx.y*32;
  int tx = threadIdx.x, ty = threadIdx.y;
  #pragma unroll
  for (int i=ty;i<32;i+=8)
    tile[i][tx] = in[(size_t)(br+i)*C + bc+tx];
  __syncthreads();
  #pragma unroll
  for (int i=ty;i<32;i+=8)
    out[(size_t)(bc+i)*R + br+tx] = f2b(tile[tx][i]);
}

__global__ void transpose_cast4(const float* __restrict__ w0, const float* __restrict__ w1,
                                const float* __restrict__ w2, const float* __restrict__ w3,
                                bf16* __restrict__ out)
{
  const float* in = blockIdx.z==0?w0 : blockIdx.z==1?w1 : blockIdx.z==2?w2 : w3;
  bf16* o = out + (size_t)blockIdx.z*768*768;
  __shared__ float tile[32][33];
  int bc = blockIdx.x*32, br = blockIdx.y*32;
  int tx = threadIdx.x, ty = threadIdx.y;
  #pragma unroll
  for (int i=ty;i<32;i+=8)
    tile[i][tx] = in[(size_t)(br+i)*768 + bc+tx];
  __syncthreads();
  #pragma unroll
  for (int i=ty;i<32;i+=8)
    o[(size_t)(bc+i)*768 + br+tx] = f2b(tile[tx][i]);
}

__global__ __launch_bounds__(256)
void castX(const float* __restrict__ in, bf16* __restrict__ out)
{
  int i = blockIdx.x*256 + threadIdx.x;
  float4 f = ((const float4*)in)[i];
  union{ unsigned long long u; __bf16 h[4]; } pk;
  pk.h[0]=(__bf16)f.x; pk.h[1]=(__bf16)f.y; pk.h[2]=(__bf16)f.z; pk.h[3]=(__bf16)f.w;
  ((unsigned long long*)out)[i] = pk.u;
}

__global__ void concat_bias(const float* __restrict__ a, const float* __restrict__ b,
                            const float* __restrict__ c, float* __restrict__ o)
{
  int i = blockIdx.x*256 + threadIdx.x;
  if (i < 768) o[i] = a[i];
  else if (i < 1536) o[i] = b[i-768];
  else if (i < 2304) o[i] = c[i-1536];
}

// V part of qkv [row][2304] -> Vt [z=(b,h)][d][s]
__global__ void vtrans(const bf16* __restrict__ v, bf16* __restrict__ vt)
{
  int z = blockIdx.z; int b = z/NHEAD, h = z - b*NHEAD;
  int d0 = blockIdx.x*32, s0 = blockIdx.y*32;
  __shared__ bf16 t[32][33];
  int tx = threadIdx.x, ty = threadIdx.y;
  #pragma unroll
  for (int i=ty;i<32;i+=8)
    t[i][tx] = v[(size_t)(b*SEQ + s0+i)*QKVW + h*HDIM + d0+tx];
  __syncthreads();
  #pragma unroll
  for (int i=ty;i<32;i+=8)
    vt[(size_t)z*HDIM*SEQ + (size_t)(d0+i)*SEQ + s0+tx] = t[tx][i];
}

// ---------------------------------------------------------------------------
// LayerNorm over 768 cols: ONE WAVE per row. (unchanged)
// ---------------------------------------------------------------------------
template<typename TO>
__global__ __launch_bounds__(256)
void ln768(const bf16* __restrict__ y, const float* __restrict__ g,
           const float* __restrict__ be, TO* __restrict__ dst)
{
  const int wave = threadIdx.x>>6, lane = threadIdx.x&63;
  const size_t row = (size_t)blockIdx.x*4 + wave;
  const bf16* yr = y + row*HID;
  float x[12];
  float s = 0.f, q = 0.f;
  #pragma unroll
  for (int c=0;c<3;c++){
    bf16x4 v = *(const bf16x4*)(yr + c*256 + lane*4);
    #pragma unroll
    for (int j=0;j<4;j++){
      float f = (float)v[j];
      x[c*4+j] = f;
      s += f; q += f*f;
    }
  }
  #pragma unroll
  for (int off=1; off<64; off<<=1){ s += __shfl_xor(s, off); q += __shfl_xor(q, off); }
  float mean = s*(1.0f/HID);
  float var  = q*(1.0f/HID) - mean*mean;
  float inv  = rsqrtf(var + 1e-12f);
  TO* dr = dst + row*HID;
  #pragma unroll
  for (int c=0;c<3;c++){
    float4 gg = *(const float4*)(g  + c*256 + lane*4);
    float4 bb = *(const float4*)(be + c*256 + lane*4);
    st4(dr + c*256 + lane*4,
        (x[c*4+0]-mean)*inv*gg.x + bb.x,
        (x[c*4+1]-mean)*inv*gg.y + bb.y,
        (x[c*4+2]-mean)*inv*gg.z + bb.z,
        (x[c*4+3]-mean)*inv*gg.w + bb.w);
  }
}

// ---------------------------------------------------------------------------
// Dialog (CLS) block: 32 rows total (unchanged)
// ---------------------------------------------------------------------------
__global__ __launch_bounds__(256)
void cls_proj(const bf16* __restrict__ x2,
              const float* __restrict__ Wq, const float* __restrict__ bq,
              const float* __restrict__ Wk, const float* __restrict__ bk,
              const float* __restrict__ Wv, const float* __restrict__ bv,
              bf16* __restrict__ oq, bf16* __restrict__ ok, bf16* __restrict__ ov)
{
  int mat = blockIdx.x, row = blockIdx.y;
  const float* W  = mat==0 ? Wq : (mat==1 ? Wk : Wv);
  const float* bi = mat==0 ? bq : (mat==1 ? bk : bv);
  bf16* out       = mat==0 ? oq : (mat==1 ? ok : ov);
  __shared__ float a[HID];
  const bf16* xr = x2 + (size_t)row*SEQ*HID;
  for (int i=threadIdx.x;i<HID;i+=256) a[i] = b2f(xr[i]);
  __syncthreads();
  for (int c0=0;c0<HID;c0+=256){
    int col = c0 + threadIdx.x;
    float acc = 0.f;
    for (int k=0;k<HID;k++) acc += a[k]*W[(size_t)k*HID + col];
    out[(size_t)row*HID + col] = f2b(acc + bi[col]);
  }
}

__global__ __launch_bounds__(64)
void cls_attn(const bf16* __restrict__ q, const bf16* __restrict__ k,
              const bf16* __restrict__ v, bf16* __restrict__ ctx)
{
  int z = blockIdx.x; int bb = z/NHEAD, h = z - bb*NHEAD;
  __shared__ float P[8][8];
  int t = threadIdx.x;
  int qi = t>>3, ki = t&7;
  float s = 0.f;
  for (int d=0; d<HDIM; d++)
    s += b2f(q[(size_t)(bb*8+qi)*HID + h*HDIM + d]) *
         b2f(k[(size_t)(bb*8+ki)*HID + h*HDIM + d]);
  s = s*0.125f + (ki >= qi ? -10000.0f : 0.0f);
  float m = s;
  #pragma unroll
  for (int off=4; off; off>>=1) m = fmaxf(m, __shfl_xor(m, off, 8));
  float e = __expf(s - m);
  float sum = e;
  #pragma unroll
  for (int off=4; off; off>>=1) sum += __shfl_xor(sum, off, 8);
  P[qi][ki] = e/sum;
  __syncthreads();
  for (int q2=0; q2<8; q2++){
    float acc = 0.f;
    #pragma unroll
    for (int k2=0; k2<8; k2++)
      acc += P[q2][k2] * b2f(v[(size_t)(bb*8+k2)*HID + h*HDIM + t]);
    ctx[(size_t)(bb*8+q2)*HID + h*HDIM + t] = f2b(acc);
  }
}

__global__ __launch_bounds__(256)
void cls_out(const bf16* __restrict__ ctx, const float* __restrict__ Wo,
             const float* __restrict__ bo, const float* __restrict__ g,
             const float* __restrict__ be, bf16* __restrict__ x2)
{
  int row = blockIdx.x;
  __shared__ float a[HID];
  __shared__ float yrow[HID];
  const bf16* cr = ctx + (size_t)row*HID;
  bf16* xr = x2 + (size_t)row*SEQ*HID;
  for (int i=threadIdx.x;i<HID;i+=256) a[i] = b2f(cr[i]);
  __syncthreads();
  for (int c0=0;c0<HID;c0+=256){
    int col = c0 + threadIdx.x;
    float acc = 0.f;
    for (int k=0;k<HID;k++) acc += a[k]*Wo[(size_t)k*HID + col];
    yrow[col] = acc + bo[col] + b2f(xr[col]);
  }
  __syncthreads();
  int t = threadIdx.x;
  float x0 = yrow[t], x1 = yrow[t+256], x2v = yrow[t+512];
  float s = x0+x1+x2v, qq = x0*x0+x1*x1+x2v*x2v;
  #pragma unroll
  for (int off=32; off; off>>=1){ s += __shfl_xor(s, off); qq += __shfl_xor(qq, off); }
  __shared__ float rs[4], rq[4];
  int wv = t>>6;
  if ((t&63)==0){ rs[wv]=s; rq[wv]=qq; }
  __syncthreads();
  s = rs[0]+rs[1]+rs[2]+rs[3];
  qq = rq[0]+rq[1]+rq[2]+rq[3];
  float mean = s*(1.0f/HID);
  float var  = qq*(1.0f/HID) - mean*mean;
  float inv  = rsqrtf(var + 1e-12f);
  xr[t    ] = f2b((x0 -mean)*inv*g[t    ] + be[t    ]);
  xr[t+256] = f2b((x1 -mean)*inv*g[t+256] + be[t+256]);
  xr[t+512] = f2b((x2v-mean)*inv*g[t+512] + be[t+512]);
}

// ---------------------------------------------------------------------------
extern "C" void kernel_launch(void* const* d_in, const int* in_sizes, int n_in,
                              void* d_out, int out_size, void* d_ws, size_t ws_size,
                              hipStream_t stream)
{
  const float* X    = (const float*)d_in[0];
  const float* AM   = (const float*)d_in[1];
  const float* Wq   = (const float*)d_in[2];  const float* bq  = (const float*)d_in[3];
  const float* Wk   = (const float*)d_in[4];  const float* bk  = (const float*)d_in[5];
  const float* Wv   = (const float*)d_in[6];  const float* bv  = (const float*)d_in[7];
  const float* Wao  = (const float*)d_in[8];  const float* bao = (const float*)d_in[9];
  const float* ln1g = (const float*)d_in[10]; const float* ln1b= (const float*)d_in[11];
  const float* dWq  = (const float*)d_in[12]; const float* dbq = (const float*)d_in[13];
  const float* dWk  = (const float*)d_in[14]; const float* dbk = (const float*)d_in[15];
  const float* dWv  = (const float*)d_in[16]; const float* dbv = (const float*)d_in[17];
  const float* dWo  = (const float*)d_in[18]; const float* dbo = (const float*)d_in[19];
  const float* dlng = (const float*)d_in[20]; const float* dlnb= (const float*)d_in[21];
  const float* Wi   = (const float*)d_in[22]; const float* bi  = (const float*)d_in[23];
  const float* Wo2  = (const float*)d_in[24]; const float* bo2 = (const float*)d_in[25];
  const float* ln2g = (const float*)d_in[26]; const float* ln2b= (const float*)d_in[27];
  float* OUT = (float*)d_out;

  char* wp = (char*)d_ws;
  auto alloc = [&](size_t elems)->bf16*{
    bf16* p = (bf16*)wp;
    wp += ((elems*sizeof(bf16) + 255)/256)*256;
    return p;
  };
  bf16* wtq  = alloc(768*768);       // wtq..wtv contiguous => fused QKV B
  bf16* wtk  = alloc(768*768);
  bf16* wtv  = alloc(768*768);
  bf16* wtao = alloc(768*768);
  bf16* wti  = alloc((size_t)768*3072);
  bf16* wto2 = alloc((size_t)3072*768);
  float* bqkv = (float*)alloc(2304*2);
  bf16* qkv  = alloc((size_t)ROWS*QKVW);          // } qkv+vtb contiguous:
  bf16* vtb  = alloc((size_t)ROWS*HID);           // } inter aliases both
  bf16* inter = qkv;
  bf16* scb  = alloc((size_t)ROWS*HID);            // y/x2 slab
  bf16* yb   = scb;
  bf16* x2   = scb;
  bf16* ctxb = alloc((size_t)ROWS*HID);
  bf16* xb   = ctxb;   // bf16 X, dead before flash writes ctxb
  bf16* clsq = alloc(32*HID);
  bf16* clsk = alloc(32*HID);
  bf16* clsv = alloc(32*HID);
  bf16* clsc = alloc(32*HID);
  (void)wtk; (void)wtv;

  dim3 T32(32,8);
  transpose_cast4<<<dim3(24,24,4), T32, 0, stream>>>(Wq, Wk, Wv, Wao, wtq);
  transpose_cast<<<dim3(96,24), T32, 0, stream>>>(Wi,  wti, 768, 3072);
  transpose_cast<<<dim3(24,96), T32, 0, stream>>>(Wo2, wto2,3072, 768);
  concat_bias<<<9,256,0,stream>>>(bq, bk, bv, bqkv);
  castX<<<ROWS*HID/4/256,256,0,stream>>>(X, xb);

  // fused QKV projection: [16384,768] @ [768,2304]^T -> qkv[row][2304]
  gemm8p<0,float><<<dim3(9,64),512,0,stream>>>(
      xb,768,  wtq,768,  qkv,QKVW, 768, bqkv, (const float*)nullptr, 0);

  vtrans<<<dim3(2,16,BATCH*NHEAD), T32, 0, stream>>>(qkv + 1536, vtb);

  // fused flash attention -> ctxb
  flash_attn<<<dim3(NCHUNK, BATCH*NHEAD),256,0,stream>>>(qkv, vtb, AM, ctxb);

  // attn out-proj + bias + residual(X fp32) -> yb ; LN1 in place -> x2
  gemm8p<2,float><<<dim3(3,64),512,0,stream>>>(
      ctxb,768,  wtao,768,  yb,768, 768, bao, X, 768);
  ln768<bf16><<<ROWS/4,256,0,stream>>>(yb, ln1g, ln1b, x2);

  // dialog (CLS) block on 32 rows
  cls_proj<<<dim3(3,32),256,0,stream>>>(x2, dWq,dbq, dWk,dbk, dWv,dbv,
                                        clsq, clsk, clsv);
  cls_attn<<<48,64,0,stream>>>(clsq, clsk, clsv, clsc);
  cls_out<<<32,256,0,stream>>>(clsc, dWo, dbo, dlng, dlnb, x2);

  // FFN1: inter = gelu(x2 @ Wi + bi)
  gemm8p<1,float><<<dim3(12,64),512,0,stream>>>(
      x2,768,  wti,768,  inter,3072, 768, bi, (const float*)nullptr, 0);
  // FFN2: y = inter @ Wo2 + bo2 + x2
  gemm8p<2,bf16><<<dim3(3,64),512,0,stream>>>(
      inter,3072,  wto2,3072,  yb,768, 3072, bo2, x2, 768);
  ln768<float><<<ROWS/4,256,0,stream>>>(yb, ln2g, ln2b, OUT);
}